// Round 2
// baseline (14323.936 us; speedup 1.0000x reference)
//
#include <hip/hip_runtime.h>
#include <hip/hip_bf16.h>

// Swin block: B=8, C=96, H=W=224, WS=7, SS=3, NH=3, HD=32, N=49, MLP_H=384
// Inputs/outputs are float32 on device; x1 scratch kept in bf16 (d_ws).

constexpr int B_  = 8;
constexpr int C_  = 96;
constexpr int H_  = 224;
constexpr int W_  = 224;
constexpr int NW_ = 1024;    // windows per batch (32*32)
constexpr long M_ = (long)C_ * H_ * W_;  // per-batch elements = 4,816,896

typedef __hip_bfloat16 bf16;

__device__ __forceinline__ float b2f(bf16 v) { return __bfloat162float(v); }

// ---------------------------------------------------------------------------
// Kernel 1: fused LN1 + shift + window partition + QKV + attention + proj +
//           "faithful-permute" residual scatter into x1 (bf16 scratch).
// One block of 256 threads per window; 8192 blocks.
// ---------------------------------------------------------------------------
__global__ __launch_bounds__(256) void attn_kernel(
    const float* __restrict__ x,
    const float* __restrict__ amask,     // (1024, 49, 49)
    const float* __restrict__ n1g, const float* __restrict__ n1b,
    const float* __restrict__ qkvw,      // (96, 288)
    const float* __restrict__ qkvb,      // (288)
    const float* __restrict__ rpb,       // (169, 3)
    const float* __restrict__ projw,     // (96, 96)
    const float* __restrict__ projb,     // (96)
    bf16* __restrict__ x1)
{
    __shared__ float xln[49][96];    // LN'd window tokens; reused for proj out
    __shared__ float qkvs[49][288];  // q|k|v per token (q pre-scaled)
    __shared__ float att[3][49][49]; // scores / probs per head
    __shared__ float outp[49][96];   // attn@v

    const int blk = blockIdx.x;
    const int b   = blk >> 10;       // / 1024
    const int wi  = blk & 1023;      // window index within batch
    const int wh  = wi >> 5, ww = wi & 31;
    const int tid = threadIdx.x;
    const long bM = (long)b * M_;

    // ---- phase 1: load shifted window ----
    for (int idx = tid; idx < 49 * 96; idx += 256) {
        int c = idx / 49;
        int t = idx % 49;
        int i = t / 7, j = t % 7;
        int h = (wh * 7 + i + 3) % 224;
        int w = (ww * 7 + j + 3) % 224;
        xln[t][c] = x[bM + (long)c * 50176 + h * 224 + w];
    }
    __syncthreads();

    // ---- LN over channels, one thread per token ----
    if (tid < 49) {
        float s = 0.f, s2 = 0.f;
        for (int c = 0; c < 96; ++c) { float v = xln[tid][c]; s += v; s2 += v * v; }
        float mu   = s * (1.0f / 96.0f);
        float var  = s2 * (1.0f / 96.0f) - mu * mu;
        float rstd = rsqrtf(var + 1e-5f);
        for (int c = 0; c < 96; ++c) {
            xln[tid][c] = (xln[tid][c] - mu) * rstd * n1g[c] + n1b[c];
        }
    }
    __syncthreads();

    // ---- phase 2: qkv = xln @ qkv_w + qkv_b ; scale q by 1/sqrt(32) ----
    for (int idx = tid; idx < 49 * 288; idx += 256) {
        int t = idx / 288, o = idx % 288;
        float acc = qkvb[o];
        for (int c = 0; c < 96; ++c)
            acc += xln[t][c] * qkvw[c * 288 + o];
        if (o < 96) acc *= 0.17677669529663689f;   // 32^-0.5
        qkvs[t][o] = acc;
    }
    __syncthreads();

    // ---- phase 3: scores = q k^T + rel-pos bias + shift mask ----
    for (int idx = tid; idx < 3 * 49 * 49; idx += 256) {
        int hd = idx / 2401;
        int r  = idx % 2401;
        int t = r / 49, u = r % 49;
        float acc = 0.f;
        const float* qq = &qkvs[t][hd * 32];
        const float* kk = &qkvs[u][96 + hd * 32];
        #pragma unroll
        for (int d = 0; d < 32; ++d) acc += qq[d] * kk[d];
        int ri = t / 7, ci = t % 7, rj = u / 7, cj = u % 7;
        int ridx = (ri - rj + 6) * 13 + (ci - cj + 6);
        acc += rpb[ridx * 3 + hd];
        acc += amask[((long)wi * 49 + t) * 49 + u];
        att[hd][t][u] = acc;
    }
    __syncthreads();

    // ---- phase 4: softmax over last dim, one thread per (head,row) ----
    if (tid < 3 * 49) {
        int hd = tid / 49, t = tid % 49;
        float mx = -1e30f;
        for (int u = 0; u < 49; ++u) mx = fmaxf(mx, att[hd][t][u]);
        float sm = 0.f;
        for (int u = 0; u < 49; ++u) {
            float e = __expf(att[hd][t][u] - mx);
            att[hd][t][u] = e;
            sm += e;
        }
        float inv = 1.0f / sm;
        for (int u = 0; u < 49; ++u) att[hd][t][u] *= inv;
    }
    __syncthreads();

    // ---- phase 5: out = attn @ v ----
    for (int idx = tid; idx < 49 * 96; idx += 256) {
        int t = idx / 96, o = idx % 96;
        int hd = o / 32;
        float acc = 0.f;
        for (int u = 0; u < 49; ++u)
            acc += att[hd][t][u] * qkvs[u][192 + o];
        outp[t][o] = acc;
    }
    __syncthreads();

    // ---- phase 6: proj (write into xln, which is dead) ----
    for (int idx = tid; idx < 49 * 96; idx += 256) {
        int t = idx / 96, c = idx % 96;
        float acc = projb[c];
        for (int k = 0; k < 96; ++k)
            acc += outp[t][k] * projw[k * 96 + c];
        xln[t][c] = acc;
    }
    __syncthreads();

    // ---- phase 7: faithful-permute residual: x1[f] = x[f] + proj_out ----
    // attention output for shifted pixel (h,w,c) lands at flat f=(h*96+c)*224+w
    for (int idx = tid; idx < 49 * 96; idx += 256) {
        int c = idx / 49;
        int t = idx % 49;
        int i = t / 7, j = t % 7;
        int h = (wh * 7 + i + 3) % 224;
        int w = (ww * 7 + j + 3) % 224;
        long f = bM + (long)(h * 96 + c) * 224 + w;
        x1[f] = __float2bfloat16(x[f] + xln[t][c]);
    }
}

// ---------------------------------------------------------------------------
// Kernel 2: MLP branch. Token t = 96 consecutive elements of the (C,W,H)
// permuted flattening: p = t*96+j -> read x1 at (c, h, w) where
// p = c*50176 + w*224 + h (h/w swapped). Final residual at flat t*96+j.
// One block of 384 threads per 16 tokens; 25088 blocks.
// ---------------------------------------------------------------------------
__global__ __launch_bounds__(384) void mlp_kernel(
    const bf16* __restrict__ x1,
    const float* __restrict__ n2g, const float* __restrict__ n2b,
    const float* __restrict__ w1, const float* __restrict__ b1,  // (96,384),(384)
    const float* __restrict__ w2, const float* __restrict__ b2,  // (384,96),(96)
    float* __restrict__ out)
{
    __shared__ float xin[16][96];
    __shared__ float hb[16][384];
    const int tid = threadIdx.x;
    const long t0 = (long)blockIdx.x * 16;   // global token base (B*50176 total)

    // ---- gather permuted x1 ----
    for (int idx = tid; idx < 16 * 96; idx += 384) {
        int tt = idx / 96, j = idx % 96;
        long tg = t0 + tt;
        long b  = tg / 50176;
        long t  = tg % 50176;
        long p  = t * 96 + j;
        int  c  = (int)(p / 50176);
        int  rem = (int)(p % 50176);
        int  w = rem / 224, h = rem % 224;
        xin[tt][j] = b2f(x1[b * M_ + (long)c * 50176 + h * 224 + w]);
    }
    __syncthreads();

    // ---- LN2, one thread per token ----
    if (tid < 16) {
        float s = 0.f, s2 = 0.f;
        for (int j = 0; j < 96; ++j) { float v = xin[tid][j]; s += v; s2 += v * v; }
        float mu   = s * (1.0f / 96.0f);
        float rstd = rsqrtf(s2 * (1.0f / 96.0f) - mu * mu + 1e-5f);
        for (int j = 0; j < 96; ++j)
            xin[tid][j] = (xin[tid][j] - mu) * rstd * n2g[j] + n2b[j];
    }
    __syncthreads();

    // ---- fc1 + exact GELU: one output column per thread (o = tid, 384) ----
    {
        const int o = tid;
        float acc[16];
        float bias = b1[o];
        #pragma unroll
        for (int tt = 0; tt < 16; ++tt) acc[tt] = bias;
        for (int c = 0; c < 96; ++c) {
            float wv = w1[c * 384 + o];
            #pragma unroll
            for (int tt = 0; tt < 16; ++tt) acc[tt] += xin[tt][c] * wv;
        }
        #pragma unroll
        for (int tt = 0; tt < 16; ++tt) {
            float v = acc[tt];
            hb[tt][o] = 0.5f * v * (1.0f + erff(v * 0.7071067811865476f));
        }
    }
    __syncthreads();

    // ---- fc2 + residual at un-permuted flat index ----
    for (int e = tid; e < 16 * 96; e += 384) {
        int tt = e / 96, c2 = e % 96;
        float acc = b2[c2];
        for (int o = 0; o < 384; ++o)
            acc += hb[tt][o] * w2[o * 96 + c2];
        long G = (t0 + tt) * 96 + c2;
        out[G] = b2f(x1[G]) + acc;
    }
}

// ---------------------------------------------------------------------------
extern "C" void kernel_launch(void* const* d_in, const int* in_sizes, int n_in,
                              void* d_out, int out_size, void* d_ws, size_t ws_size,
                              hipStream_t stream) {
    const float* x      = (const float*)d_in[0];
    const float* amask  = (const float*)d_in[1];
    const float* n1g    = (const float*)d_in[2];
    const float* n1b    = (const float*)d_in[3];
    const float* qkvw   = (const float*)d_in[4];
    const float* qkvb   = (const float*)d_in[5];
    const float* rpb    = (const float*)d_in[6];
    const float* projw  = (const float*)d_in[7];
    const float* projb  = (const float*)d_in[8];
    const float* n2g    = (const float*)d_in[9];
    const float* n2b    = (const float*)d_in[10];
    const float* w1     = (const float*)d_in[11];
    const float* b1     = (const float*)d_in[12];
    const float* w2     = (const float*)d_in[13];
    const float* b2     = (const float*)d_in[14];

    bf16* x1 = (bf16*)d_ws;   // 38,535,168 bf16 = 77.1 MB scratch
    float* out = (float*)d_out;

    attn_kernel<<<dim3(B_ * NW_), dim3(256), 0, stream>>>(
        x, amask, n1g, n1b, qkvw, qkvb, rpb, projw, projb, x1);

    mlp_kernel<<<dim3((B_ * 50176) / 16), dim3(384), 0, stream>>>(
        x1, n2g, n2b, w1, b1, w2, b2, out);
}

// Round 3
// 4062.536 us; speedup vs baseline: 3.5259x; 3.5259x over previous
//
#include <hip/hip_runtime.h>
#include <hip/hip_bf16.h>

// Swin block: B=8, C=96, H=W=224, WS=7, SS=3, NH=3, HD=32, N=49, MLP_H=384
// Inputs/outputs fp32; x1 scratch bf16 in d_ws.

constexpr int B_  = 8;
constexpr int NW_ = 1024;                 // windows per batch (32*32)
constexpr int M_  = 96 * 224 * 224;       // per-batch elements = 4,816,896

typedef __hip_bfloat16 bf16;
__device__ __forceinline__ float b2f(bf16 v) { return __bfloat162float(v); }

// ---------------------------------------------------------------------------
// attn: LN1 + shift + window + QKV + MHA + proj + faithful-permute residual.
// 256 threads (4 waves) per window, 8192 blocks.
// LDS = xln[49][97] (19.0 KB) + qk[49][292] (57.2 KB) = 76.2 KB -> 2 blk/CU.
// Waves 0..2 = heads; lane t = token; k/v reads are LDS broadcasts (no bank
// conflicts); score row lives in 49 registers per lane.
// ---------------------------------------------------------------------------
__global__ __launch_bounds__(256) void attn_kernel(
    const float* __restrict__ x,
    const float* __restrict__ amask,     // (1024, 49, 49)
    const float* __restrict__ n1g, const float* __restrict__ n1b,
    const float* __restrict__ qkvw,      // (96, 288)
    const float* __restrict__ qkvb,      // (288)
    const float* __restrict__ rpb,       // (169, 3)
    const float* __restrict__ projw,     // (96, 96)
    const float* __restrict__ projb,     // (96)
    bf16* __restrict__ x1)
{
    __shared__ __align__(16) float xln[49][97];   // LN'd tokens; later rpb stage + attn-out
    __shared__ __align__(16) float qk[49][292];   // q|k|v fp32 (rows 292 for b128-friendly, odd/4 banks)

    const int tid  = threadIdx.x;
    const int wave = tid >> 6, lane = tid & 63;
    const int blk  = blockIdx.x;
    const int b    = blk >> 10;
    const int wi   = blk & 1023;
    const int wh   = wi >> 5, ww = wi & 31;
    const int bM   = b * M_;
    const bool need_mask = (wh == 31) || (ww == 31);

    // ---- phase 1: load shifted window ----
    for (int idx = tid; idx < 49 * 96; idx += 256) {
        int c = idx / 49, t = idx % 49;
        int i = t / 7, j = t % 7;
        int h = (wh * 7 + i + 3) % 224;
        int w = (ww * 7 + j + 3) % 224;
        xln[t][c] = x[bM + c * 50176 + h * 224 + w];
    }
    __syncthreads();

    // ---- LN1: 4 lanes per token, shfl-reduced ----
    if (tid < 196) {
        int t = tid >> 2, s = tid & 3;
        float sum = 0.f, sq = 0.f;
        #pragma unroll
        for (int i = 0; i < 24; ++i) { float v = xln[t][s * 24 + i]; sum += v; sq += v * v; }
        sum += __shfl_xor(sum, 1); sq += __shfl_xor(sq, 1);
        sum += __shfl_xor(sum, 2); sq += __shfl_xor(sq, 2);
        float mu   = sum * (1.0f / 96.0f);
        float rstd = rsqrtf(sq * (1.0f / 96.0f) - mu * mu + 1e-5f);
        #pragma unroll
        for (int i = 0; i < 24; ++i) {
            int c = s * 24 + i;
            xln[t][c] = (xln[t][c] - mu) * rstd * n1g[c] + n1b[c];
        }
    }
    __syncthreads();

    // ---- phase 2: qkv = xln @ qkv_w + b (14112 outs, quads of 4 indep accs) ----
    constexpr float QS = 0.17677669529663689f;   // 32^-0.5
    for (int k = 0; k < 14; ++k) {
        int i0 = (k << 10) + tid;
        if (i0 >= 14112) break;
        int i1 = i0 + 256, i2 = i0 + 512, i3 = i0 + 768;
        bool v1 = i1 < 14112, v2 = i2 < 14112, v3 = i3 < 14112;
        int j1 = v1 ? i1 : i0, j2 = v2 ? i2 : i0, j3 = v3 ? i3 : i0;
        int t0 = i0 / 288, o0 = i0 % 288;
        int t1 = j1 / 288, o1 = j1 % 288;
        int t2 = j2 / 288, o2 = j2 % 288;
        int t3 = j3 / 288, o3 = j3 % 288;
        float a0 = qkvb[o0], a1 = qkvb[o1], a2 = qkvb[o2], a3 = qkvb[o3];
        #pragma unroll 4
        for (int c = 0; c < 96; ++c) {
            const float* wr = &qkvw[c * 288];
            a0 += xln[t0][c] * wr[o0];
            a1 += xln[t1][c] * wr[o1];
            a2 += xln[t2][c] * wr[o2];
            a3 += xln[t3][c] * wr[o3];
        }
        if (o0 < 96) a0 *= QS;
        qk[t0][o0] = a0;
        if (v1) { if (o1 < 96) a1 *= QS; qk[t1][o1] = a1; }
        if (v2) { if (o2 < 96) a2 *= QS; qk[t2][o2] = a2; }
        if (v3) { if (o3 < 96) a3 *= QS; qk[t3][o3] = a3; }
    }
    __syncthreads();

    // ---- stage rpb into dead xln space ----
    float* rpb_s = &xln[0][0];
    for (int i = tid; i < 507; i += 256) rpb_s[i] = rpb[i];
    __syncthreads();

    // ---- phase 3+4: scores + softmax (wave=head, lane=token) ----
    const int  hd  = wave;
    const int  t   = lane;
    const bool act = (hd < 3) && (t < 49);
    float sc[49];
    float inv = 0.f;
    if (act) {
        float q[32];
        #pragma unroll
        for (int i = 0; i < 8; ++i) {
            float4 qv = *(const float4*)&qk[t][hd * 32 + 4 * i];
            q[4*i] = qv.x; q[4*i+1] = qv.y; q[4*i+2] = qv.z; q[4*i+3] = qv.w;
        }
        const int ri = t / 7, ci = t % 7;
        const int rbase = (ri * 13 + ci) * 3 + hd + 252;   // (6*13+6)*3
        const float* mrow = &amask[(wi * 49 + t) * 49];
        #pragma unroll
        for (int u = 0; u < 49; ++u) {
            float a0 = 0.f, a1 = 0.f, a2 = 0.f, a3 = 0.f;
            #pragma unroll
            for (int i = 0; i < 8; ++i) {
                float4 kv = *(const float4*)&qk[u][96 + hd * 32 + 4 * i];
                a0 += q[4*i]   * kv.x; a1 += q[4*i+1] * kv.y;
                a2 += q[4*i+2] * kv.z; a3 += q[4*i+3] * kv.w;
            }
            float a = (a0 + a1) + (a2 + a3);
            a += rpb_s[rbase - ((u / 7) * 13 + (u % 7)) * 3];
            if (need_mask) a += mrow[u];
            sc[u] = a;
        }
        float m0 = sc[0], m1 = sc[1];
        #pragma unroll
        for (int u = 2; u < 48; u += 2) { m0 = fmaxf(m0, sc[u]); m1 = fmaxf(m1, sc[u + 1]); }
        float mx = fmaxf(fmaxf(m0, m1), sc[48]);
        float s0 = 0.f, s1 = 0.f;
        #pragma unroll
        for (int u = 0; u < 49; ++u) {
            float e = __expf(sc[u] - mx);
            sc[u] = e;
            if (u & 1) s1 += e; else s0 += e;
        }
        inv = 1.0f / (s0 + s1);
    }
    __syncthreads();   // rpb_s fully consumed before xln is overwritten

    // ---- phase 5: out = attn @ v -> xln[t][0..95] ----
    if (act) {
        float o[32];
        #pragma unroll
        for (int i = 0; i < 32; ++i) o[i] = 0.f;
        #pragma unroll
        for (int u = 0; u < 49; ++u) {
            float p = sc[u];
            #pragma unroll
            for (int i = 0; i < 8; ++i) {
                float4 vv = *(const float4*)&qk[u][192 + hd * 32 + 4 * i];
                o[4*i]   += p * vv.x; o[4*i+1] += p * vv.y;
                o[4*i+2] += p * vv.z; o[4*i+3] += p * vv.w;
            }
        }
        #pragma unroll
        for (int i = 0; i < 32; ++i) xln[t][hd * 32 + i] = o[i] * inv;
    }
    __syncthreads();

    // ---- phase 6: proj -> qk[t][c] (4704 outs, quads) ----
    for (int k = 0; k < 5; ++k) {
        int i0 = (k << 10) + tid;
        if (i0 >= 4704) break;
        int i1 = i0 + 256, i2 = i0 + 512, i3 = i0 + 768;
        bool v1 = i1 < 4704, v2 = i2 < 4704, v3 = i3 < 4704;
        int j1 = v1 ? i1 : i0, j2 = v2 ? i2 : i0, j3 = v3 ? i3 : i0;
        int t0 = i0 / 96, c0 = i0 % 96;
        int t1 = j1 / 96, c1 = j1 % 96;
        int t2 = j2 / 96, c2 = j2 % 96;
        int t3 = j3 / 96, c3 = j3 % 96;
        float a0 = projb[c0], a1 = projb[c1], a2 = projb[c2], a3 = projb[c3];
        #pragma unroll 4
        for (int kk = 0; kk < 96; ++kk) {
            const float* wr = &projw[kk * 96];
            a0 += xln[t0][kk] * wr[c0];
            a1 += xln[t1][kk] * wr[c1];
            a2 += xln[t2][kk] * wr[c2];
            a3 += xln[t3][kk] * wr[c3];
        }
        qk[t0][c0] = a0;
        if (v1) qk[t1][c1] = a1;
        if (v2) qk[t2][c2] = a2;
        if (v3) qk[t3][c3] = a3;
    }
    __syncthreads();

    // ---- phase 7: faithful-permute residual into x1 ----
    for (int idx = tid; idx < 4704; idx += 256) {
        int c = idx / 49, t2 = idx % 49;
        int i = t2 / 7, j = t2 % 7;
        int h = (wh * 7 + i + 3) % 224;
        int w = (ww * 7 + j + 3) % 224;
        int f = bM + (h * 96 + c) * 224 + w;
        x1[f] = __float2bfloat16(x[f] + qk[t2][c]);
    }
}

// ---------------------------------------------------------------------------
// MLP: gather permuted x1 -> LN2 -> fc1+GELU -> fc2 + residual.
// 384 threads per 16 tokens; 25088 blocks. LDS 30.8 KB -> 5 blk/CU (30 waves).
// ---------------------------------------------------------------------------
__global__ __launch_bounds__(384) void mlp_kernel(
    const bf16* __restrict__ x1,
    const float* __restrict__ n2g, const float* __restrict__ n2b,
    const float* __restrict__ w1, const float* __restrict__ b1,  // (96,384),(384)
    const float* __restrict__ w2, const float* __restrict__ b2,  // (384,96),(96)
    float* __restrict__ out)
{
    __shared__ float xin[16][97];
    __shared__ float hb[16][384];
    const int tid = threadIdx.x;
    const int t0  = blockIdx.x * 16;   // global token base (B*50176 total)

    // ---- gather permuted x1: p = t*96+j -> read at (c, h, w), p=c*50176+w*224+h
    for (int idx = tid; idx < 1536; idx += 384) {
        int tt = idx / 96, j = idx % 96;
        int tg = t0 + tt;
        int bb = tg / 50176;
        int t  = tg % 50176;
        int p  = t * 96 + j;
        int c  = p / 50176;
        int rem = p % 50176;
        int w = rem / 224, h = rem % 224;
        xin[tt][j] = b2f(x1[bb * M_ + c * 50176 + h * 224 + w]);
    }
    __syncthreads();

    // ---- LN2: 4 lanes per token ----
    if (tid < 64) {
        int t = tid >> 2, s = tid & 3;
        float sum = 0.f, sq = 0.f;
        #pragma unroll
        for (int i = 0; i < 24; ++i) { float v = xin[t][s * 24 + i]; sum += v; sq += v * v; }
        sum += __shfl_xor(sum, 1); sq += __shfl_xor(sq, 1);
        sum += __shfl_xor(sum, 2); sq += __shfl_xor(sq, 2);
        float mu   = sum * (1.0f / 96.0f);
        float rstd = rsqrtf(sq * (1.0f / 96.0f) - mu * mu + 1e-5f);
        #pragma unroll
        for (int i = 0; i < 24; ++i) {
            int c = s * 24 + i;
            xin[t][c] = (xin[t][c] - mu) * rstd * n2g[c] + n2b[c];
        }
    }
    __syncthreads();

    // ---- fc1 + exact GELU: column o = tid, 16 token accs ----
    {
        const int o = tid;
        float acc[16];
        float bias = b1[o];
        #pragma unroll
        for (int tt = 0; tt < 16; ++tt) acc[tt] = bias;
        for (int c = 0; c < 96; ++c) {
            float wv = w1[c * 384 + o];
            #pragma unroll
            for (int tt = 0; tt < 16; ++tt) acc[tt] += xin[tt][c] * wv;
        }
        #pragma unroll
        for (int tt = 0; tt < 16; ++tt) {
            float v = acc[tt];
            hb[tt][o] = 0.5f * v * (1.0f + erff(v * 0.7071067811865476f));
        }
    }
    __syncthreads();

    // ---- fc2 + residual: 4 outputs/thread sharing each weight load ----
    {
        const int c2 = tid % 96;
        const int tb = tid / 96;           // 0..3
        float a0 = b2[c2], a1 = a0, a2 = a0, a3 = a0;
        #pragma unroll 4
        for (int o = 0; o < 384; ++o) {
            float wv = w2[o * 96 + c2];
            a0 += hb[tb][o]      * wv;
            a1 += hb[tb + 4][o]  * wv;
            a2 += hb[tb + 8][o]  * wv;
            a3 += hb[tb + 12][o] * wv;
        }
        int G0 = (t0 + tb) * 96 + c2;
        out[G0]            = b2f(x1[G0])            + a0;
        out[G0 + 4  * 96]  = b2f(x1[G0 + 4  * 96])  + a1;
        out[G0 + 8  * 96]  = b2f(x1[G0 + 8  * 96])  + a2;
        out[G0 + 12 * 96]  = b2f(x1[G0 + 12 * 96])  + a3;
    }
}

// ---------------------------------------------------------------------------
extern "C" void kernel_launch(void* const* d_in, const int* in_sizes, int n_in,
                              void* d_out, int out_size, void* d_ws, size_t ws_size,
                              hipStream_t stream) {
    const float* x      = (const float*)d_in[0];
    const float* amask  = (const float*)d_in[1];
    const float* n1g    = (const float*)d_in[2];
    const float* n1b    = (const float*)d_in[3];
    const float* qkvw   = (const float*)d_in[4];
    const float* qkvb   = (const float*)d_in[5];
    const float* rpb    = (const float*)d_in[6];
    const float* projw  = (const float*)d_in[7];
    const float* projb  = (const float*)d_in[8];
    const float* n2g    = (const float*)d_in[9];
    const float* n2b    = (const float*)d_in[10];
    const float* w1     = (const float*)d_in[11];
    const float* b1     = (const float*)d_in[12];
    const float* w2     = (const float*)d_in[13];
    const float* b2     = (const float*)d_in[14];

    bf16* x1 = (bf16*)d_ws;   // 38,535,168 bf16 = 77.1 MB scratch
    float* out = (float*)d_out;

    attn_kernel<<<dim3(B_ * NW_), dim3(256), 0, stream>>>(
        x, amask, n1g, n1b, qkvw, qkvb, rpb, projw, projb, x1);

    mlp_kernel<<<dim3((B_ * 50176) / 16), dim3(384), 0, stream>>>(
        x1, n2g, n2b, w1, b1, w2, b2, out);
}

// Round 5
// 1183.979 us; speedup vs baseline: 12.0981x; 3.4313x over previous
//
#include <hip/hip_runtime.h>
#include <hip/hip_bf16.h>

// Swin block B=8,C=96,H=W=224,WS=7,SS=3,NH=3,HD=32,N=49(pad 64),MLP_H=384
// fp32 in/out; bf16 MFMA (16x16x32) for qkv/QK^T/PV/proj/fc1/fc2.
// d_ws layout: [0,270KB) packed bf16 transposed weights; [256KB,...) x1 bf16.

typedef __attribute__((ext_vector_type(4))) float f32x4;
typedef __attribute__((ext_vector_type(8))) short s16x8;

constexpr int B_ = 8;
constexpr int M_ = 96 * 224 * 224;   // 4,816,896 per-batch elements

__device__ __forceinline__ ushort f2bs(float f) {
    __hip_bfloat16 h = __float2bfloat16(f);
    ushort u; __builtin_memcpy(&u, &h, 2); return u;
}
__device__ __forceinline__ float bs2f(ushort u) {
    __hip_bfloat16 h; __builtin_memcpy(&h, &u, 2); return __bfloat162float(h);
}
__device__ __forceinline__ f32x4 mfma16(s16x8 a, s16x8 b, f32x4 c) {
    return __builtin_amdgcn_mfma_f32_16x16x32_bf16(a, b, c, 0, 0, 0);
}

// ---------------------------------------------------------------------------
// prep: pack transposed bf16 weights. wq[288][96], wp[96][96], wf1[384][96],
// wf2[96][384]. 144 blocks x 256.
// ---------------------------------------------------------------------------
__global__ __launch_bounds__(256) void prep_kernel(
    const float* __restrict__ qkvw, const float* __restrict__ projw,
    const float* __restrict__ w1,   const float* __restrict__ w2,
    ushort* __restrict__ wq, ushort* __restrict__ wp,
    ushort* __restrict__ wf1, ushort* __restrict__ wf2)
{
    int i = blockIdx.x * 256 + threadIdx.x;
    if (i < 27648) { int n = i / 96, k = i % 96;  wq[i]  = f2bs(qkvw[k * 288 + n]); }
    if (i < 9216)  { int n = i / 96, k = i % 96;  wp[i]  = f2bs(projw[k * 96 + n]); }
    if (i < 36864) {
        int n = i / 96,  k = i % 96;   wf1[i] = f2bs(w1[k * 384 + n]);
        int n2 = i / 384, k2 = i % 384; wf2[i] = f2bs(w2[k2 * 96 + n2]);
    }
}

// ---------------------------------------------------------------------------
// attn: LN1+shift+window+QKV+MHA+proj+faithful residual. 1 window / block,
// 256 thr (4 waves), 8192 blocks. LDS 75.5 KB -> 2 blocks/CU.
// ---------------------------------------------------------------------------
__global__ __launch_bounds__(256) void attn_kernel(
    const float* __restrict__ x,
    const float* __restrict__ amask,
    const float* __restrict__ n1g, const float* __restrict__ n1b,
    const float* __restrict__ qkvb,
    const float* __restrict__ rpb,
    const float* __restrict__ projb,
    const ushort* __restrict__ wq, const ushort* __restrict__ wp,
    ushort* __restrict__ x1)
{
    __shared__ __align__(16) ushort xa[64][104];   // LN'd tokens; later proj-out
    __shared__ __align__(16) ushort qk[64][200];   // [t][q 0..95 | k 96..191 | pad]
    __shared__ __align__(16) ushort vT[96][72];    // [d][t]
    __shared__ __align__(16) ushort Pws[4][16][72];// per-wave P slab [row][u]
    __shared__ __align__(16) ushort Ob[64][104];   // attn-out [t][d]
    __shared__ float rpbs[512];

    const int tid  = threadIdx.x;
    const int wave = tid >> 6, lane = tid & 63;
    const int cu   = lane & 15;          // col within 16-tile
    const int g4   = lane >> 4;          // lane group 0..3
    const int gk8  = g4 << 3;            // k-chunk offset (8 elems)
    const int gr4  = g4 << 2;            // D-frag row offset (4 rows)

    const int blk = blockIdx.x;
    const int b   = blk >> 10;
    const int wi  = blk & 1023;
    const int wh  = wi >> 5, ww = wi & 31;
    const int bM  = b * M_;
    const bool need_mask = (wh == 31) || (ww == 31);

    // stage rpb
    for (int i = tid; i < 507; i += 256) rpbs[i] = rpb[i];

    // phase 1: load shifted window (pad rows 49..63 = 0)
    for (int idx = tid; idx < 6144; idx += 256) {
        int c = idx >> 6, t = idx & 63;
        float v = 0.f;
        if (t < 49) {
            int i = t / 7, j = t % 7;
            int hh = (wh * 7 + i + 3) % 224;
            int wcol = (ww * 7 + j + 3) % 224;
            v = x[bM + c * 50176 + hh * 224 + wcol];
        }
        xa[t][c] = f2bs(v);
    }
    __syncthreads();

    // LN1: 4 lanes per token (t<49)
    if (tid < 196) {
        int t = tid >> 2, s = tid & 3;
        float sum = 0.f, sq = 0.f;
        float vv[24];
        #pragma unroll
        for (int i = 0; i < 24; ++i) {
            vv[i] = bs2f(xa[t][s * 24 + i]);
            sum += vv[i]; sq += vv[i] * vv[i];
        }
        sum += __shfl_xor(sum, 1); sq += __shfl_xor(sq, 1);
        sum += __shfl_xor(sum, 2); sq += __shfl_xor(sq, 2);
        float mu   = sum * (1.0f / 96.0f);
        float rstd = rsqrtf(sq * (1.0f / 96.0f) - mu * mu + 1e-5f);
        #pragma unroll
        for (int i = 0; i < 24; ++i) {
            int c = s * 24 + i;
            xa[t][c] = f2bs((vv[i] - mu) * rstd * n1g[c] + n1b[c]);
        }
    }
    __syncthreads();

    // qkv GEMM: wave owns M-tile=wave; 18 N-tiles x 3 K
    {
        const int ar = (wave << 4) | cu;
        s16x8 a0 = *(const s16x8*)&xa[ar][gk8];
        s16x8 a1 = *(const s16x8*)&xa[ar][32 + gk8];
        s16x8 a2 = *(const s16x8*)&xa[ar][64 + gk8];
        const int tr = (wave << 4) + gr4;
        for (int nt = 0; nt < 18; ++nt) {
            int nc = (nt << 4) | cu;
            const ushort* bp = wq + nc * 96 + gk8;
            s16x8 b0 = *(const s16x8*)(bp);
            s16x8 b1 = *(const s16x8*)(bp + 32);
            s16x8 b2 = *(const s16x8*)(bp + 64);
            f32x4 acc = {0.f, 0.f, 0.f, 0.f};
            acc = mfma16(a0, b0, acc);
            acc = mfma16(a1, b1, acc);
            acc = mfma16(a2, b2, acc);
            float bias = qkvb[nc];
            if (nc < 192) {
                float s = (nc < 96) ? 0.17677669529663689f : 1.0f;
                #pragma unroll
                for (int r = 0; r < 4; ++r) qk[tr + r][nc] = f2bs((acc[r] + bias) * s);
            } else {
                int d = nc - 192;
                ushort4 pk;
                pk.x = f2bs(acc[0] + bias); pk.y = f2bs(acc[1] + bias);
                pk.z = f2bs(acc[2] + bias); pk.w = f2bs(acc[3] + bias);
                *(ushort4*)&vT[d][tr] = pk;
            }
        }
    }
    __syncthreads();

    // scores + softmax + PV: 12 tasks (head,ttile), 3 per wave
    for (int it = 0; it < 3; ++it) {
        int task = wave * 3 + it;
        int hh = task >> 2, tt = task & 3;
        const int t0r = (tt << 4) + gr4;

        s16x8 aq = *(const s16x8*)&qk[(tt << 4) | cu][(hh << 5) + gk8];
        f32x4 sa[4];
        #pragma unroll
        for (int ut = 0; ut < 4; ++ut) {
            s16x8 bk = *(const s16x8*)&qk[(ut << 4) | cu][96 + (hh << 5) + gk8];
            f32x4 z = {0.f, 0.f, 0.f, 0.f};
            sa[ut] = mfma16(aq, bk, z);
        }
        // rel-pos bias + shift mask + pad masking
        #pragma unroll
        for (int ut = 0; ut < 4; ++ut) {
            int u = (ut << 4) | cu;
            #pragma unroll
            for (int r = 0; r < 4; ++r) {
                int t = t0r + r;
                float s = sa[ut][r];
                if (t < 49 && u < 49) {
                    int dr = t / 7 - u / 7 + 6, dc = t % 7 - u % 7 + 6;
                    s += rpbs[(dr * 13 + dc) * 3 + hh];
                    if (need_mask) s += amask[(wi * 49 + t) * 49 + u];
                } else if (u >= 49) {
                    s = -1e30f;
                }
                sa[ut][r] = s;
            }
        }
        // softmax per row (16-lane groups hold a row)
        float inv[4];
        #pragma unroll
        for (int r = 0; r < 4; ++r) {
            float m = fmaxf(fmaxf(sa[0][r], sa[1][r]), fmaxf(sa[2][r], sa[3][r]));
            m = fmaxf(m, __shfl_xor(m, 1)); m = fmaxf(m, __shfl_xor(m, 2));
            m = fmaxf(m, __shfl_xor(m, 4)); m = fmaxf(m, __shfl_xor(m, 8));
            float e0 = __expf(sa[0][r] - m), e1 = __expf(sa[1][r] - m);
            float e2 = __expf(sa[2][r] - m), e3 = __expf(sa[3][r] - m);
            sa[0][r] = e0; sa[1][r] = e1; sa[2][r] = e2; sa[3][r] = e3;
            float s = (e0 + e1) + (e2 + e3);
            s += __shfl_xor(s, 1); s += __shfl_xor(s, 2);
            s += __shfl_xor(s, 4); s += __shfl_xor(s, 8);
            inv[r] = 1.0f / s;
        }
        // P -> wave-private slab (bf16, un-normalized)
        #pragma unroll
        for (int ut = 0; ut < 4; ++ut) {
            int u = (ut << 4) | cu;
            #pragma unroll
            for (int r = 0; r < 4; ++r) Pws[wave][gr4 + r][u] = f2bs(sa[ut][r]);
        }
        // PV: O[t][32d] for this (hh,tt)
        s16x8 pa0 = *(const s16x8*)&Pws[wave][cu][gk8];
        s16x8 pa1 = *(const s16x8*)&Pws[wave][cu][32 + gk8];
        #pragma unroll
        for (int nt = 0; nt < 2; ++nt) {
            int d = (hh << 5) + (nt << 4) + cu;
            s16x8 bv0 = *(const s16x8*)&vT[d][gk8];
            s16x8 bv1 = *(const s16x8*)&vT[d][32 + gk8];
            f32x4 acc = {0.f, 0.f, 0.f, 0.f};
            acc = mfma16(pa0, bv0, acc);
            acc = mfma16(pa1, bv1, acc);
            #pragma unroll
            for (int r = 0; r < 4; ++r) Ob[t0r + r][d] = f2bs(acc[r] * inv[r]);
        }
    }
    __syncthreads();

    // proj GEMM: wave owns M-tile; 6 N x 3 K; out -> xa (bf16)
    {
        const int ar = (wave << 4) | cu;
        s16x8 a0 = *(const s16x8*)&Ob[ar][gk8];
        s16x8 a1 = *(const s16x8*)&Ob[ar][32 + gk8];
        s16x8 a2 = *(const s16x8*)&Ob[ar][64 + gk8];
        const int tr = (wave << 4) + gr4;
        for (int nt = 0; nt < 6; ++nt) {
            int nc = (nt << 4) | cu;
            const ushort* bp = wp + nc * 96 + gk8;
            s16x8 b0 = *(const s16x8*)(bp);
            s16x8 b1 = *(const s16x8*)(bp + 32);
            s16x8 b2 = *(const s16x8*)(bp + 64);
            f32x4 acc = {0.f, 0.f, 0.f, 0.f};
            acc = mfma16(a0, b0, acc);
            acc = mfma16(a1, b1, acc);
            acc = mfma16(a2, b2, acc);
            float bias = projb[nc];
            #pragma unroll
            for (int r = 0; r < 4; ++r) xa[tr + r][nc] = f2bs(acc[r] + bias);
        }
    }
    __syncthreads();

    // phase 7: faithful-permute residual: x1[f] = x[f] + proj_out[t][c]
    for (int idx = tid; idx < 4704; idx += 256) {
        int c = idx / 49, t = idx % 49;
        int i = t / 7, j = t % 7;
        int hh = (wh * 7 + i + 3) % 224;
        int wcol = (ww * 7 + j + 3) % 224;
        int f = bM + (hh * 96 + c) * 224 + wcol;
        x1[f] = f2bs(x[f] + bs2f(xa[t][c]));
    }
}

// ---------------------------------------------------------------------------
// MLP: gather permuted x1 -> LN2 -> fc1+GELU(MFMA) -> fc2(MFMA)+residual.
// 64 tokens / block, 256 thr, 6272 blocks. LDS 62 KB -> 2 blocks/CU.
// ---------------------------------------------------------------------------
__global__ __launch_bounds__(256) void mlp_kernel(
    const ushort* __restrict__ x1,
    const float* __restrict__ n2g, const float* __restrict__ n2b,
    const float* __restrict__ b1v, const float* __restrict__ b2v,
    const ushort* __restrict__ wf1, const ushort* __restrict__ wf2,
    float* __restrict__ out)
{
    __shared__ __align__(16) ushort xin[64][104];
    __shared__ __align__(16) ushort hB[64][392];

    const int tid  = threadIdx.x;
    const int wave = tid >> 6, lane = tid & 63;
    const int cu   = lane & 15;
    const int g4   = lane >> 4;
    const int gk8  = g4 << 3;
    const int gr4  = g4 << 2;
    const int t0   = blockIdx.x * 64;

    // gather permuted x1: p=t*96+j -> (c,h,w) with p=c*50176+w*224+h
    for (int idx = tid; idx < 6144; idx += 256) {
        int tt = idx / 96, j = idx % 96;
        int tg = t0 + tt;
        int bb = tg / 50176;
        int t  = tg % 50176;
        int p  = t * 96 + j;
        int c  = p / 50176;
        int rem = p % 50176;
        int w = rem / 224, h2 = rem % 224;
        xin[tt][j] = x1[bb * M_ + c * 50176 + h2 * 224 + w];
    }
    __syncthreads();

    // LN2: 64 tokens x 4 lanes
    {
        int t = tid >> 2, s = tid & 3;
        float sum = 0.f, sq = 0.f;
        float vv[24];
        #pragma unroll
        for (int i = 0; i < 24; ++i) {
            vv[i] = bs2f(xin[t][s * 24 + i]);
            sum += vv[i]; sq += vv[i] * vv[i];
        }
        sum += __shfl_xor(sum, 1); sq += __shfl_xor(sq, 1);
        sum += __shfl_xor(sum, 2); sq += __shfl_xor(sq, 2);
        float mu   = sum * (1.0f / 96.0f);
        float rstd = rsqrtf(sq * (1.0f / 96.0f) - mu * mu + 1e-5f);
        #pragma unroll
        for (int i = 0; i < 24; ++i) {
            int c = s * 24 + i;
            xin[t][c] = f2bs((vv[i] - mu) * rstd * n2g[c] + n2b[c]);
        }
    }
    __syncthreads();

    // fc1 + exact GELU: wave owns M-tile; 24 N x 3 K
    {
        const int ar = (wave << 4) | cu;
        s16x8 a0 = *(const s16x8*)&xin[ar][gk8];
        s16x8 a1 = *(const s16x8*)&xin[ar][32 + gk8];
        s16x8 a2 = *(const s16x8*)&xin[ar][64 + gk8];
        const int tr = (wave << 4) + gr4;
        for (int nt = 0; nt < 24; ++nt) {
            int nc = (nt << 4) | cu;
            const ushort* bp = wf1 + nc * 96 + gk8;
            s16x8 b0 = *(const s16x8*)(bp);
            s16x8 b1 = *(const s16x8*)(bp + 32);
            s16x8 b2 = *(const s16x8*)(bp + 64);
            f32x4 acc = {0.f, 0.f, 0.f, 0.f};
            acc = mfma16(a0, b0, acc);
            acc = mfma16(a1, b1, acc);
            acc = mfma16(a2, b2, acc);
            float bias = b1v[nc];
            #pragma unroll
            for (int r = 0; r < 4; ++r) {
                float v = acc[r] + bias;
                v = 0.5f * v * (1.0f + erff(v * 0.7071067811865476f));
                hB[tr + r][nc] = f2bs(v);
            }
        }
    }
    __syncthreads();

    // fc2 + residual: wave owns M-tile; A-frags (12) in regs; 6 N x 12 K
    {
        const int ar = (wave << 4) | cu;
        s16x8 ha[12];
        #pragma unroll
        for (int ks = 0; ks < 12; ++ks)
            ha[ks] = *(const s16x8*)&hB[ar][ks * 32 + gk8];
        const int tr = (wave << 4) + gr4;
        for (int nt = 0; nt < 6; ++nt) {
            int nc = (nt << 4) | cu;
            f32x4 acc = {0.f, 0.f, 0.f, 0.f};
            #pragma unroll
            for (int ks = 0; ks < 12; ++ks) {
                s16x8 bb = *(const s16x8*)&wf2[nc * 384 + ks * 32 + gk8];
                acc = mfma16(ha[ks], bb, acc);
            }
            float bias = b2v[nc];
            #pragma unroll
            for (int r = 0; r < 4; ++r) {
                int G = (t0 + tr + r) * 96 + nc;
                out[G] = bias + acc[r] + bs2f(x1[G]);
            }
        }
    }
}

// ---------------------------------------------------------------------------
extern "C" void kernel_launch(void* const* d_in, const int* in_sizes, int n_in,
                              void* d_out, int out_size, void* d_ws, size_t ws_size,
                              hipStream_t stream) {
    const float* x      = (const float*)d_in[0];
    const float* amask  = (const float*)d_in[1];
    const float* n1g    = (const float*)d_in[2];
    const float* n1b    = (const float*)d_in[3];
    const float* qkvw   = (const float*)d_in[4];
    const float* qkvb   = (const float*)d_in[5];
    const float* rpb    = (const float*)d_in[6];
    const float* projw  = (const float*)d_in[7];
    const float* projb  = (const float*)d_in[8];
    const float* n2g    = (const float*)d_in[9];
    const float* n2b    = (const float*)d_in[10];
    const float* w1     = (const float*)d_in[11];
    const float* b1     = (const float*)d_in[12];
    const float* w2     = (const float*)d_in[13];
    const float* b2     = (const float*)d_in[14];

    char* ws = (char*)d_ws;
    ushort* wq  = (ushort*)(ws);            // 27648 el
    ushort* wp  = (ushort*)(ws + 55296);    // 9216 el
    ushort* wf1 = (ushort*)(ws + 73728);    // 36864 el
    ushort* wf2 = (ushort*)(ws + 147456);   // 36864 el
    ushort* x1  = (ushort*)(ws + 262144);   // 38,535,168 el (77.07 MB)
    float* out = (float*)d_out;

    prep_kernel<<<dim3(144), dim3(256), 0, stream>>>(qkvw, projw, w1, w2, wq, wp, wf1, wf2);

    attn_kernel<<<dim3(8192), dim3(256), 0, stream>>>(
        x, amask, n1g, n1b, qkvb, rpb, projb, wq, wp, x1);

    mlp_kernel<<<dim3(6272), dim3(256), 0, stream>>>(
        x1, n2g, n2b, b1, b2, wf1, wf2, out);
}

// Round 6
// 1030.699 us; speedup vs baseline: 13.8973x; 1.1487x over previous
//
#include <hip/hip_runtime.h>
#include <hip/hip_bf16.h>

// Swin block B=8,C=96,H=W=224,WS=7,SS=3,NH=3,HD=32,N=49(pad 64),MLP_H=384
// fp32 in/out; bf16 MFMA (16x16x32) for qkv/QK^T/PV/proj/fc1/fc2.
// d_ws layout: [0,270KB) packed bf16 transposed weights; [256KB,...) x1 bf16.

typedef __attribute__((ext_vector_type(4))) float f32x4;
typedef __attribute__((ext_vector_type(8))) short s16x8;

constexpr int B_ = 8;
constexpr int M_ = 96 * 224 * 224;   // 4,816,896 per-batch elements

__device__ __forceinline__ ushort f2bs(float f) {
    __hip_bfloat16 h = __float2bfloat16(f);
    ushort u; __builtin_memcpy(&u, &h, 2); return u;
}
__device__ __forceinline__ float bs2f(ushort u) {
    __hip_bfloat16 h; __builtin_memcpy(&h, &u, 2); return __bfloat162float(h);
}
__device__ __forceinline__ f32x4 mfma16(s16x8 a, s16x8 b, f32x4 c) {
    return __builtin_amdgcn_mfma_f32_16x16x32_bf16(a, b, c, 0, 0, 0);
}

// ---------------------------------------------------------------------------
// prep: pack transposed bf16 weights. wq[288][96], wp[96][96], wf1[384][96],
// wf2[96][384]. 144 blocks x 256.
// ---------------------------------------------------------------------------
__global__ __launch_bounds__(256) void prep_kernel(
    const float* __restrict__ qkvw, const float* __restrict__ projw,
    const float* __restrict__ w1,   const float* __restrict__ w2,
    ushort* __restrict__ wq, ushort* __restrict__ wp,
    ushort* __restrict__ wf1, ushort* __restrict__ wf2)
{
    int i = blockIdx.x * 256 + threadIdx.x;
    if (i < 27648) { int n = i / 96, k = i % 96;  wq[i]  = f2bs(qkvw[k * 288 + n]); }
    if (i < 9216)  { int n = i / 96, k = i % 96;  wp[i]  = f2bs(projw[k * 96 + n]); }
    if (i < 36864) {
        int n = i / 96,  k = i % 96;   wf1[i] = f2bs(w1[k * 384 + n]);
        int n2 = i / 384, k2 = i % 384; wf2[i] = f2bs(w2[k2 * 96 + n2]);
    }
}

// ---------------------------------------------------------------------------
// attn: LN1+shift+window+QKV+MHA+proj+faithful residual. 1 window / block,
// 256 thr (4 waves), 8192 blocks, XCD-swizzled. LDS 75.5 KB -> 2 blocks/CU.
// ---------------------------------------------------------------------------
__global__ __launch_bounds__(256) void attn_kernel(
    const float* __restrict__ x,
    const float* __restrict__ amask,
    const float* __restrict__ n1g, const float* __restrict__ n1b,
    const float* __restrict__ qkvb,
    const float* __restrict__ rpb,
    const float* __restrict__ projb,
    const ushort* __restrict__ wq, const ushort* __restrict__ wp,
    ushort* __restrict__ x1)
{
    __shared__ __align__(16) ushort xa[64][104];   // LN'd tokens; later proj-out
    __shared__ __align__(16) ushort qk[64][200];   // [t][q 0..95 | k 96..191 | pad]
    __shared__ __align__(16) ushort vT[96][72];    // [d][t]
    __shared__ __align__(16) ushort Pws[4][16][72];// per-wave P slab [row][u]
    __shared__ __align__(16) ushort Ob[64][104];   // attn-out [t][d]
    __shared__ float rpbs[512];

    const int tid  = threadIdx.x;
    const int wave = tid >> 6, lane = tid & 63;
    const int cu   = lane & 15;          // col within 16-tile
    const int g4   = lane >> 4;          // lane group 0..3
    const int gk8  = g4 << 3;            // k-chunk offset (8 elems)
    const int gr4  = g4 << 2;            // D-frag row offset (4 rows)

    // XCD swizzle: consecutive windows (adjacent w) on the same XCD L2
    const int blk = (blockIdx.x & 7) * 1024 + (blockIdx.x >> 3);
    const int b   = blk >> 10;
    const int wi  = blk & 1023;
    const int wh  = wi >> 5, ww = wi & 31;
    const int bM  = b * M_;
    const bool need_mask = (wh == 31) || (ww == 31);

    // stage rpb
    for (int i = tid; i < 507; i += 256) rpbs[i] = rpb[i];

    // phase 1: load shifted window (pad rows 49..63 = 0)
    for (int idx = tid; idx < 6144; idx += 256) {
        int c = idx >> 6, t = idx & 63;
        float v = 0.f;
        if (t < 49) {
            int i = t / 7, j = t % 7;
            int hh = (wh * 7 + i + 3) % 224;
            int wcol = (ww * 7 + j + 3) % 224;
            v = x[bM + c * 50176 + hh * 224 + wcol];
        }
        xa[t][c] = f2bs(v);
    }
    __syncthreads();

    // LN1: 4 lanes per token (t<49)
    if (tid < 196) {
        int t = tid >> 2, s = tid & 3;
        float sum = 0.f, sq = 0.f;
        float vv[24];
        #pragma unroll
        for (int i = 0; i < 24; ++i) {
            vv[i] = bs2f(xa[t][s * 24 + i]);
            sum += vv[i]; sq += vv[i] * vv[i];
        }
        sum += __shfl_xor(sum, 1); sq += __shfl_xor(sq, 1);
        sum += __shfl_xor(sum, 2); sq += __shfl_xor(sq, 2);
        float mu   = sum * (1.0f / 96.0f);
        float rstd = rsqrtf(sq * (1.0f / 96.0f) - mu * mu + 1e-5f);
        #pragma unroll
        for (int i = 0; i < 24; ++i) {
            int c = s * 24 + i;
            xa[t][c] = f2bs((vv[i] - mu) * rstd * n1g[c] + n1b[c]);
        }
    }
    __syncthreads();

    // qkv GEMM: wave owns M-tile=wave; 18 N-tiles x 3 K
    {
        const int ar = (wave << 4) | cu;
        s16x8 a0 = *(const s16x8*)&xa[ar][gk8];
        s16x8 a1 = *(const s16x8*)&xa[ar][32 + gk8];
        s16x8 a2 = *(const s16x8*)&xa[ar][64 + gk8];
        const int tr = (wave << 4) + gr4;
        for (int nt = 0; nt < 18; ++nt) {
            int nc = (nt << 4) | cu;
            const ushort* bp = wq + nc * 96 + gk8;
            s16x8 b0 = *(const s16x8*)(bp);
            s16x8 b1 = *(const s16x8*)(bp + 32);
            s16x8 b2 = *(const s16x8*)(bp + 64);
            f32x4 acc = {0.f, 0.f, 0.f, 0.f};
            acc = mfma16(a0, b0, acc);
            acc = mfma16(a1, b1, acc);
            acc = mfma16(a2, b2, acc);
            float bias = qkvb[nc];
            if (nc < 192) {
                float s = (nc < 96) ? 0.17677669529663689f : 1.0f;
                #pragma unroll
                for (int r = 0; r < 4; ++r) qk[tr + r][nc] = f2bs((acc[r] + bias) * s);
            } else {
                int d = nc - 192;
                ushort4 pk;
                pk.x = f2bs(acc[0] + bias); pk.y = f2bs(acc[1] + bias);
                pk.z = f2bs(acc[2] + bias); pk.w = f2bs(acc[3] + bias);
                *(ushort4*)&vT[d][tr] = pk;
            }
        }
    }
    __syncthreads();

    // scores + softmax + PV: 12 tasks (head,ttile), 3 per wave
    for (int it = 0; it < 3; ++it) {
        int task = wave * 3 + it;
        int hh = task >> 2, tt = task & 3;
        const int t0r = (tt << 4) + gr4;

        s16x8 aq = *(const s16x8*)&qk[(tt << 4) | cu][(hh << 5) + gk8];
        f32x4 sa[4];
        #pragma unroll
        for (int ut = 0; ut < 4; ++ut) {
            s16x8 bk = *(const s16x8*)&qk[(ut << 4) | cu][96 + (hh << 5) + gk8];
            f32x4 z = {0.f, 0.f, 0.f, 0.f};
            sa[ut] = mfma16(aq, bk, z);
        }
        // rel-pos bias + shift mask + pad masking
        #pragma unroll
        for (int ut = 0; ut < 4; ++ut) {
            int u = (ut << 4) | cu;
            #pragma unroll
            for (int r = 0; r < 4; ++r) {
                int t = t0r + r;
                float s = sa[ut][r];
                if (t < 49 && u < 49) {
                    int dr = t / 7 - u / 7 + 6, dc = t % 7 - u % 7 + 6;
                    s += rpbs[(dr * 13 + dc) * 3 + hh];
                    if (need_mask) s += amask[(wi * 49 + t) * 49 + u];
                } else if (u >= 49) {
                    s = -1e30f;
                }
                sa[ut][r] = s;
            }
        }
        // softmax per row (16-lane groups hold a row)
        float inv[4];
        #pragma unroll
        for (int r = 0; r < 4; ++r) {
            float m = fmaxf(fmaxf(sa[0][r], sa[1][r]), fmaxf(sa[2][r], sa[3][r]));
            m = fmaxf(m, __shfl_xor(m, 1)); m = fmaxf(m, __shfl_xor(m, 2));
            m = fmaxf(m, __shfl_xor(m, 4)); m = fmaxf(m, __shfl_xor(m, 8));
            float e0 = __expf(sa[0][r] - m), e1 = __expf(sa[1][r] - m);
            float e2 = __expf(sa[2][r] - m), e3 = __expf(sa[3][r] - m);
            sa[0][r] = e0; sa[1][r] = e1; sa[2][r] = e2; sa[3][r] = e3;
            float s = (e0 + e1) + (e2 + e3);
            s += __shfl_xor(s, 1); s += __shfl_xor(s, 2);
            s += __shfl_xor(s, 4); s += __shfl_xor(s, 8);
            inv[r] = 1.0f / s;
        }
        // P -> wave-private slab (bf16, un-normalized)
        #pragma unroll
        for (int ut = 0; ut < 4; ++ut) {
            int u = (ut << 4) | cu;
            #pragma unroll
            for (int r = 0; r < 4; ++r) Pws[wave][gr4 + r][u] = f2bs(sa[ut][r]);
        }
        // PV: O[t][32d] for this (hh,tt)
        s16x8 pa0 = *(const s16x8*)&Pws[wave][cu][gk8];
        s16x8 pa1 = *(const s16x8*)&Pws[wave][cu][32 + gk8];
        #pragma unroll
        for (int nt = 0; nt < 2; ++nt) {
            int d = (hh << 5) + (nt << 4) + cu;
            s16x8 bv0 = *(const s16x8*)&vT[d][gk8];
            s16x8 bv1 = *(const s16x8*)&vT[d][32 + gk8];
            f32x4 acc = {0.f, 0.f, 0.f, 0.f};
            acc = mfma16(pa0, bv0, acc);
            acc = mfma16(pa1, bv1, acc);
            #pragma unroll
            for (int r = 0; r < 4; ++r) Ob[t0r + r][d] = f2bs(acc[r] * inv[r]);
        }
    }
    __syncthreads();

    // proj GEMM: wave owns M-tile; 6 N x 3 K; out -> xa (bf16)
    {
        const int ar = (wave << 4) | cu;
        s16x8 a0 = *(const s16x8*)&Ob[ar][gk8];
        s16x8 a1 = *(const s16x8*)&Ob[ar][32 + gk8];
        s16x8 a2 = *(const s16x8*)&Ob[ar][64 + gk8];
        const int tr = (wave << 4) + gr4;
        for (int nt = 0; nt < 6; ++nt) {
            int nc = (nt << 4) | cu;
            const ushort* bp = wp + nc * 96 + gk8;
            s16x8 b0 = *(const s16x8*)(bp);
            s16x8 b1 = *(const s16x8*)(bp + 32);
            s16x8 b2 = *(const s16x8*)(bp + 64);
            f32x4 acc = {0.f, 0.f, 0.f, 0.f};
            acc = mfma16(a0, b0, acc);
            acc = mfma16(a1, b1, acc);
            acc = mfma16(a2, b2, acc);
            float bias = projb[nc];
            #pragma unroll
            for (int r = 0; r < 4; ++r) xa[tr + r][nc] = f2bs(acc[r] + bias);
        }
    }
    __syncthreads();

    // phase 7: faithful-permute residual: x1[f] = x[f] + proj_out[t][c]
    for (int idx = tid; idx < 4704; idx += 256) {
        int c = idx / 49, t = idx % 49;
        int i = t / 7, j = t % 7;
        int hh = (wh * 7 + i + 3) % 224;
        int wcol = (ww * 7 + j + 3) % 224;
        int f = bM + (hh * 96 + c) * 224 + wcol;
        x1[f] = f2bs(x[f] + bs2f(xa[t][c]));
    }
}

// ---------------------------------------------------------------------------
// MLP: tiled gather of permuted x1 -> LN2 -> fc1+GELU(MFMA) -> fc2(MFMA)+res.
// 64 tokens / block, 256 thr, 6272 blocks XCD-swizzled. LDS 62 KB -> 2 blk/CU.
// Gather: 64 tokens = 6144 consecutive p; p = (c*224+w)*224 + h, so the block
// needs <=29 consecutive (c,w) columns x all h. Stage [29 cols][224 h] tile
// with w-fast coalesced reads, then assemble tokens from LDS.
// ---------------------------------------------------------------------------
__global__ __launch_bounds__(256) void mlp_kernel(
    const ushort* __restrict__ x1,
    const float* __restrict__ n2g, const float* __restrict__ n2b,
    const float* __restrict__ b1v, const float* __restrict__ b2v,
    const ushort* __restrict__ wf1, const ushort* __restrict__ wf2,
    float* __restrict__ out)
{
    __shared__ __align__(16) ushort xin[64][104];
    __shared__ __align__(16) ushort hB[64][392];   // also aliased as gather tile
    ushort (*lds_g)[224] = (ushort(*)[224])&hB[0][0];  // [29][224] = 12.7 KB

    const int tid  = threadIdx.x;
    const int wave = tid >> 6, lane = tid & 63;
    const int cu   = lane & 15;
    const int g4   = lane >> 4;
    const int gk8  = g4 << 3;
    const int gr4  = g4 << 2;

    // XCD swizzle (6272 = 8 * 784)
    const int blk = (blockIdx.x & 7) * 784 + (blockIdx.x >> 3);
    const int t0g = blk * 64;              // global token base
    const int bb  = t0g / 50176;
    const int P0  = (t0g % 50176) * 96;    // within-batch permuted base (mult of 6144)
    const int CW0 = P0 / 224;              // first (c*224+w) column index
    const int bMb = bb * M_;

    // stage gather tile: lds_g[s][h] = x1[bMb + c*50176 + h*224 + w], CW=CW0+s
    for (int idx = tid; idx < 32 * 224; idx += 256) {
        int s = idx & 31, hh = idx >> 5;
        int CW = CW0 + s;
        if (s < 29 && CW < 21504) {
            int c = CW / 224, w = CW % 224;
            lds_g[s][hh] = x1[bMb + c * 50176 + hh * 224 + w];
        }
    }
    __syncthreads();

    // assemble tokens: xin[tt][j] = tile value at p = P0 + tt*96 + j
    for (int idx = tid; idx < 6144; idx += 256) {
        int tt = idx / 96, j = idx % 96;
        int p = P0 + tt * 96 + j;
        xin[tt][j] = lds_g[p / 224 - CW0][p % 224];
    }
    __syncthreads();

    // LN2: 64 tokens x 4 lanes
    {
        int t = tid >> 2, s = tid & 3;
        float sum = 0.f, sq = 0.f;
        float vv[24];
        #pragma unroll
        for (int i = 0; i < 24; ++i) {
            vv[i] = bs2f(xin[t][s * 24 + i]);
            sum += vv[i]; sq += vv[i] * vv[i];
        }
        sum += __shfl_xor(sum, 1); sq += __shfl_xor(sq, 1);
        sum += __shfl_xor(sum, 2); sq += __shfl_xor(sq, 2);
        float mu   = sum * (1.0f / 96.0f);
        float rstd = rsqrtf(sq * (1.0f / 96.0f) - mu * mu + 1e-5f);
        #pragma unroll
        for (int i = 0; i < 24; ++i) {
            int c = s * 24 + i;
            xin[t][c] = f2bs((vv[i] - mu) * rstd * n2g[c] + n2b[c]);
        }
    }
    __syncthreads();

    // fc1 + exact GELU: wave owns M-tile; 24 N x 3 K
    {
        const int ar = (wave << 4) | cu;
        s16x8 a0 = *(const s16x8*)&xin[ar][gk8];
        s16x8 a1 = *(const s16x8*)&xin[ar][32 + gk8];
        s16x8 a2 = *(const s16x8*)&xin[ar][64 + gk8];
        const int tr = (wave << 4) + gr4;
        for (int nt = 0; nt < 24; ++nt) {
            int nc = (nt << 4) | cu;
            const ushort* bp = wf1 + nc * 96 + gk8;
            s16x8 b0 = *(const s16x8*)(bp);
            s16x8 b1 = *(const s16x8*)(bp + 32);
            s16x8 b2 = *(const s16x8*)(bp + 64);
            f32x4 acc = {0.f, 0.f, 0.f, 0.f};
            acc = mfma16(a0, b0, acc);
            acc = mfma16(a1, b1, acc);
            acc = mfma16(a2, b2, acc);
            float bias = b1v[nc];
            #pragma unroll
            for (int r = 0; r < 4; ++r) {
                float v = acc[r] + bias;
                v = 0.5f * v * (1.0f + erff(v * 0.7071067811865476f));
                hB[tr + r][nc] = f2bs(v);
            }
        }
    }
    __syncthreads();

    // fc2 + residual: wave owns M-tile; A-frags (12) in regs; 6 N x 12 K
    {
        const int ar = (wave << 4) | cu;
        s16x8 ha[12];
        #pragma unroll
        for (int ks = 0; ks < 12; ++ks)
            ha[ks] = *(const s16x8*)&hB[ar][ks * 32 + gk8];
        const int tr = (wave << 4) + gr4;
        for (int nt = 0; nt < 6; ++nt) {
            int nc = (nt << 4) | cu;
            f32x4 acc = {0.f, 0.f, 0.f, 0.f};
            #pragma unroll
            for (int ks = 0; ks < 12; ++ks) {
                s16x8 bv = *(const s16x8*)&wf2[nc * 384 + ks * 32 + gk8];
                acc = mfma16(ha[ks], bv, acc);
            }
            float bias = b2v[nc];
            #pragma unroll
            for (int r = 0; r < 4; ++r) {
                int G = (t0g + tr + r) * 96 + nc;
                out[G] = bias + acc[r] + bs2f(x1[G]);
            }
        }
    }
}

// ---------------------------------------------------------------------------
extern "C" void kernel_launch(void* const* d_in, const int* in_sizes, int n_in,
                              void* d_out, int out_size, void* d_ws, size_t ws_size,
                              hipStream_t stream) {
    const float* x      = (const float*)d_in[0];
    const float* amask  = (const float*)d_in[1];
    const float* n1g    = (const float*)d_in[2];
    const float* n1b    = (const float*)d_in[3];
    const float* qkvw   = (const float*)d_in[4];
    const float* qkvb   = (const float*)d_in[5];
    const float* rpb    = (const float*)d_in[6];
    const float* projw  = (const float*)d_in[7];
    const float* projb  = (const float*)d_in[8];
    const float* n2g    = (const float*)d_in[9];
    const float* n2b    = (const float*)d_in[10];
    const float* w1     = (const float*)d_in[11];
    const float* b1     = (const float*)d_in[12];
    const float* w2     = (const float*)d_in[13];
    const float* b2     = (const float*)d_in[14];

    char* ws = (char*)d_ws;
    ushort* wq  = (ushort*)(ws);            // 27648 el
    ushort* wp  = (ushort*)(ws + 55296);    // 9216 el
    ushort* wf1 = (ushort*)(ws + 73728);    // 36864 el
    ushort* wf2 = (ushort*)(ws + 147456);   // 36864 el
    ushort* x1  = (ushort*)(ws + 262144);   // 38,535,168 el (77.07 MB)
    float* out = (float*)d_out;

    prep_kernel<<<dim3(144), dim3(256), 0, stream>>>(qkvw, projw, w1, w2, wq, wp, wf1, wf2);

    attn_kernel<<<dim3(8192), dim3(256), 0, stream>>>(
        x, amask, n1g, n1b, qkvb, rpb, projb, wq, wp, x1);

    mlp_kernel<<<dim3(6272), dim3(256), 0, stream>>>(
        x1, n2g, n2b, b1, b2, wf1, wf2, out);
}

// Round 8
// 817.853 us; speedup vs baseline: 17.5141x; 1.2602x over previous
//
#include <hip/hip_runtime.h>
#include <hip/hip_bf16.h>

// Swin block B=8,C=96,H=W=224,WS=7,SS=3,NH=3,HD=32,N=49(pad 64),MLP_H=384
// fp32 in/out; bf16 MFMA (16x16x32). d_ws: weights | x1 (flat) | x1p (permuted).

typedef __attribute__((ext_vector_type(4))) float f32x4;
typedef __attribute__((ext_vector_type(8))) short s16x8;

constexpr int B_ = 8;
constexpr int M_ = 96 * 224 * 224;   // 4,816,896 per-batch elements

__device__ __forceinline__ ushort f2bs(float f) {
    __hip_bfloat16 h = __float2bfloat16(f);
    ushort u; __builtin_memcpy(&u, &h, 2); return u;
}
__device__ __forceinline__ float bs2f(ushort u) {
    __hip_bfloat16 h; __builtin_memcpy(&h, &u, 2); return __bfloat162float(h);
}
__device__ __forceinline__ f32x4 mfma16(s16x8 a, s16x8 b, f32x4 c) {
    return __builtin_amdgcn_mfma_f32_16x16x32_bf16(a, b, c, 0, 0, 0);
}

// ---------------------------------------------------------------------------
// prep: pack transposed bf16 weights.
// ---------------------------------------------------------------------------
__global__ __launch_bounds__(256) void prep_kernel(
    const float* __restrict__ qkvw, const float* __restrict__ projw,
    const float* __restrict__ w1,   const float* __restrict__ w2,
    ushort* __restrict__ wq, ushort* __restrict__ wp,
    ushort* __restrict__ wf1, ushort* __restrict__ wf2)
{
    int i = blockIdx.x * 256 + threadIdx.x;
    if (i < 27648) { int n = i / 96, k = i % 96;  wq[i]  = f2bs(qkvw[k * 288 + n]); }
    if (i < 9216)  { int n = i / 96, k = i % 96;  wp[i]  = f2bs(projw[k * 96 + n]); }
    if (i < 36864) {
        int n = i / 96,  k = i % 96;   wf1[i] = f2bs(w1[k * 384 + n]);
        int n2 = i / 384, k2 = i % 384; wf2[i] = f2bs(w2[k2 * 96 + n2]);
    }
}

// ---------------------------------------------------------------------------
// attn: LN1+shift+window+QKV+MHA+proj+faithful residual. 1 window / block,
// 256 thr (4 waves), 8192 blocks XCD-swizzled. LDS 50.5 KB -> 3 blocks/CU.
// Wave w owns M-tile w; tasks (hh=0..2, tt=wave) -> q and O are wave-private.
// ---------------------------------------------------------------------------
__global__ __launch_bounds__(256) void attn_kernel(
    const float* __restrict__ x,
    const float* __restrict__ amask,
    const float* __restrict__ n1g, const float* __restrict__ n1b,
    const float* __restrict__ qkvb,
    const float* __restrict__ rpb,
    const float* __restrict__ projb,
    const ushort* __restrict__ wq, const ushort* __restrict__ wp,
    ushort* __restrict__ x1)
{
    __shared__ __align__(16) ushort T[64][104];    // tokens -> q -> proj-out
    __shared__ __align__(16) ushort K[64][104];    // k -> O (attn out)
    __shared__ __align__(16) ushort vT[96][72];    // [d][t]
    __shared__ __align__(16) ushort Pws[4][16][72];// per-wave P slab
    __shared__ float rpbs[512];

    const int tid  = threadIdx.x;
    const int wave = tid >> 6, lane = tid & 63;
    const int cu   = lane & 15;
    const int g4   = lane >> 4;
    const int gk8  = g4 << 3;
    const int gr4  = g4 << 2;

    // XCD swizzle: consecutive windows (adjacent ww) on same XCD L2
    const int blk = (blockIdx.x & 7) * 1024 + (blockIdx.x >> 3);
    const int b   = blk >> 10;
    const int wi  = blk & 1023;
    const int wh  = wi >> 5, ww = wi & 31;
    const int bM  = b * M_;
    const bool need_mask = (wh == 31) || (ww == 31);

    for (int i = tid; i < 507; i += 256) rpbs[i] = rpb[i];

    // phase 1: load shifted window (pad rows 49..63 = 0)
    for (int idx = tid; idx < 6144; idx += 256) {
        int c = idx >> 6, t = idx & 63;
        float v = 0.f;
        if (t < 49) {
            int i = t / 7, j = t % 7;
            int hh = (wh * 7 + i + 3) % 224;
            int wcol = (ww * 7 + j + 3) % 224;
            v = x[bM + c * 50176 + hh * 224 + wcol];
        }
        T[t][c] = f2bs(v);
    }
    __syncthreads();   // B1

    // LN1: 4 lanes per token (t<49); thread->token mapping is wave-aligned
    if (tid < 196) {
        int t = tid >> 2, s = tid & 3;
        float sum = 0.f, sq = 0.f;
        float vv[24];
        #pragma unroll
        for (int i = 0; i < 24; ++i) {
            vv[i] = bs2f(T[t][s * 24 + i]);
            sum += vv[i]; sq += vv[i] * vv[i];
        }
        sum += __shfl_xor(sum, 1); sq += __shfl_xor(sq, 1);
        sum += __shfl_xor(sum, 2); sq += __shfl_xor(sq, 2);
        float mu   = sum * (1.0f / 96.0f);
        float rstd = rsqrtf(sq * (1.0f / 96.0f) - mu * mu + 1e-5f);
        #pragma unroll
        for (int i = 0; i < 24; ++i) {
            int c = s * 24 + i;
            T[t][c] = f2bs((vv[i] - mu) * rstd * n1g[c] + n1b[c]);
        }
    }
    __syncthreads();   // B2

    const int ar = (wave << 4) | cu;
    const int tr = (wave << 4) + gr4;

    // qkv GEMM: wave owns M-tile; q -> regs, k -> K LDS, v -> vT LDS
    {
        s16x8 a0 = *(const s16x8*)&T[ar][gk8];
        s16x8 a1 = *(const s16x8*)&T[ar][32 + gk8];
        s16x8 a2 = *(const s16x8*)&T[ar][64 + gk8];
        f32x4 qreg[6];
        #pragma unroll
        for (int nt = 0; nt < 18; ++nt) {
            int nc = (nt << 4) | cu;
            const ushort* bp = wq + nc * 96 + gk8;
            s16x8 b0 = *(const s16x8*)(bp);
            s16x8 b1 = *(const s16x8*)(bp + 32);
            s16x8 b2 = *(const s16x8*)(bp + 64);
            f32x4 acc = {0.f, 0.f, 0.f, 0.f};
            acc = mfma16(a0, b0, acc);
            acc = mfma16(a1, b1, acc);
            acc = mfma16(a2, b2, acc);
            float bias = qkvb[nc];
            if (nt < 6) {
                #pragma unroll
                for (int r = 0; r < 4; ++r)
                    qreg[nt][r] = (acc[r] + bias) * 0.17677669529663689f;
            } else if (nc < 192) {
                #pragma unroll
                for (int r = 0; r < 4; ++r) K[tr + r][nc - 96] = f2bs(acc[r] + bias);
            } else {
                int d = nc - 192;
                ushort4 pk;
                pk.x = f2bs(acc[0] + bias); pk.y = f2bs(acc[1] + bias);
                pk.z = f2bs(acc[2] + bias); pk.w = f2bs(acc[3] + bias);
                *(ushort4*)&vT[d][tr] = pk;
            }
        }
        // write q into T (own rows; token data fully consumed by this wave)
        #pragma unroll
        for (int qn = 0; qn < 6; ++qn)
            #pragma unroll
            for (int r = 0; r < 4; ++r)
                T[tr + r][(qn << 4) | cu] = f2bs(qreg[qn][r]);
    }
    __syncthreads();   // B3

    // tasks: (hh=0..2, tt=wave). O accumulated in registers.
    f32x4 osc[3][2];
    #pragma unroll
    for (int it = 0; it < 3; ++it) {
        const int hh = it;
        const int t0r = tr;

        s16x8 aq = *(const s16x8*)&T[ar][(hh << 5) + gk8];
        f32x4 sa[4];
        #pragma unroll
        for (int ut = 0; ut < 4; ++ut) {
            s16x8 bk = *(const s16x8*)&K[(ut << 4) | cu][(hh << 5) + gk8];
            f32x4 z = {0.f, 0.f, 0.f, 0.f};
            sa[ut] = mfma16(aq, bk, z);
        }
        #pragma unroll
        for (int ut = 0; ut < 4; ++ut) {
            int u = (ut << 4) | cu;
            #pragma unroll
            for (int r = 0; r < 4; ++r) {
                int t = t0r + r;
                float s = sa[ut][r];
                if (t < 49 && u < 49) {
                    int dr = t / 7 - u / 7 + 6, dc = t % 7 - u % 7 + 6;
                    s += rpbs[(dr * 13 + dc) * 3 + hh];
                    if (need_mask) s += amask[(wi * 49 + t) * 49 + u];
                } else if (u >= 49) {
                    s = -1e30f;
                }
                sa[ut][r] = s;
            }
        }
        float inv[4];
        #pragma unroll
        for (int r = 0; r < 4; ++r) {
            float m = fmaxf(fmaxf(sa[0][r], sa[1][r]), fmaxf(sa[2][r], sa[3][r]));
            m = fmaxf(m, __shfl_xor(m, 1)); m = fmaxf(m, __shfl_xor(m, 2));
            m = fmaxf(m, __shfl_xor(m, 4)); m = fmaxf(m, __shfl_xor(m, 8));
            float e0 = __expf(sa[0][r] - m), e1 = __expf(sa[1][r] - m);
            float e2 = __expf(sa[2][r] - m), e3 = __expf(sa[3][r] - m);
            sa[0][r] = e0; sa[1][r] = e1; sa[2][r] = e2; sa[3][r] = e3;
            float s = (e0 + e1) + (e2 + e3);
            s += __shfl_xor(s, 1); s += __shfl_xor(s, 2);
            s += __shfl_xor(s, 4); s += __shfl_xor(s, 8);
            inv[r] = 1.0f / s;
        }
        #pragma unroll
        for (int ut = 0; ut < 4; ++ut) {
            int u = (ut << 4) | cu;
            #pragma unroll
            for (int r = 0; r < 4; ++r) Pws[wave][gr4 + r][u] = f2bs(sa[ut][r]);
        }
        s16x8 pa0 = *(const s16x8*)&Pws[wave][cu][gk8];
        s16x8 pa1 = *(const s16x8*)&Pws[wave][cu][32 + gk8];
        #pragma unroll
        for (int nt = 0; nt < 2; ++nt) {
            int d = (hh << 5) + (nt << 4) + cu;
            s16x8 bv0 = *(const s16x8*)&vT[d][gk8];
            s16x8 bv1 = *(const s16x8*)&vT[d][32 + gk8];
            f32x4 acc = {0.f, 0.f, 0.f, 0.f};
            acc = mfma16(pa0, bv0, acc);
            acc = mfma16(pa1, bv1, acc);
            #pragma unroll
            for (int r = 0; r < 4; ++r) osc[it][nt][r] = acc[r] * inv[r];
        }
    }
    __syncthreads();   // B4: all K reads complete

    // O -> K (own rows)
    #pragma unroll
    for (int it = 0; it < 3; ++it)
        #pragma unroll
        for (int nt = 0; nt < 2; ++nt)
            #pragma unroll
            for (int r = 0; r < 4; ++r)
                K[tr + r][(it << 5) + (nt << 4) + cu] = f2bs(osc[it][nt][r]);

    // proj: A from K (own rows), out -> T (own rows)
    {
        s16x8 a0 = *(const s16x8*)&K[ar][gk8];
        s16x8 a1 = *(const s16x8*)&K[ar][32 + gk8];
        s16x8 a2 = *(const s16x8*)&K[ar][64 + gk8];
        #pragma unroll
        for (int nt = 0; nt < 6; ++nt) {
            int nc = (nt << 4) | cu;
            const ushort* bp = wp + nc * 96 + gk8;
            s16x8 b0 = *(const s16x8*)(bp);
            s16x8 b1 = *(const s16x8*)(bp + 32);
            s16x8 b2 = *(const s16x8*)(bp + 64);
            f32x4 acc = {0.f, 0.f, 0.f, 0.f};
            acc = mfma16(a0, b0, acc);
            acc = mfma16(a1, b1, acc);
            acc = mfma16(a2, b2, acc);
            float bias = projb[nc];
            #pragma unroll
            for (int r = 0; r < 4; ++r) T[tr + r][nc] = f2bs(acc[r] + bias);
        }
    }
    __syncthreads();   // B5

    // faithful-permute residual: x1[f] = x[f] + proj_out[t][c]
    for (int idx = tid; idx < 4704; idx += 256) {
        int c = idx / 49, t = idx % 49;
        int i = t / 7, j = t % 7;
        int hh = (wh * 7 + i + 3) % 224;
        int wcol = (ww * 7 + j + 3) % 224;
        int f = bM + (hh * 96 + c) * 224 + wcol;
        x1[f] = f2bs(x[f] + bs2f(T[t][c]));
    }
}

// ---------------------------------------------------------------------------
// transpose: per (b,c) slab, x1p[base + w*224 + h] = x1[base + h*224 + w],
// base = (b*96+c)*50176. This makes MLP token rows contiguous:
// x1p[p] with p = c*50176 + w*224 + h equals x1.flat[c*50176 + h*224 + w].
// 32x32 tiles: 768 slabs * 49 tiles = 37632 blocks x 256.
// ---------------------------------------------------------------------------
__global__ __launch_bounds__(256) void transpose_kernel(
    const ushort* __restrict__ x1, ushort* __restrict__ x1p)
{
    __shared__ ushort tile[32][36];   // stride 36: 8B-aligned ushort4 rows
    const int id      = blockIdx.x;
    const int tile_id = id % 49;
    const int slab    = id / 49;          // b*96 + c
    const int h0 = (tile_id / 7) * 32;
    const int w0 = (tile_id % 7) * 32;
    const ushort* src = x1  + slab * 50176;
    ushort*       dst = x1p + slab * 50176;

    const int i = threadIdx.x >> 3;       // 0..31
    const int j = (threadIdx.x & 7) * 4;  // 0,4,...,28

    *(ushort4*)&tile[i][j] = *(const ushort4*)&src[(h0 + i) * 224 + w0 + j];
    __syncthreads();
    ushort4 v;
    v.x = tile[j][i]; v.y = tile[j + 1][i]; v.z = tile[j + 2][i]; v.w = tile[j + 3][i];
    *(ushort4*)&dst[(w0 + i) * 224 + h0 + j] = v;
}

// ---------------------------------------------------------------------------
// MLP: reg-LN (no xin LDS, no barriers) -> fc1+GELU -> fc2 + residual.
// 64 tokens / block, 256 thr, 6272 blocks. LDS 49 KB -> 3 blocks/CU.
// CLEAN: read contiguous token rows from x1p. else: scattered gather from x1.
// ---------------------------------------------------------------------------
template <bool CLEAN>
__global__ __launch_bounds__(256) void mlp_kernel(
    const ushort* __restrict__ xsrc,
    const ushort* __restrict__ x1flat,
    const float* __restrict__ n2g, const float* __restrict__ n2b,
    const float* __restrict__ b1v, const float* __restrict__ b2v,
    const ushort* __restrict__ wf1, const ushort* __restrict__ wf2,
    float* __restrict__ out)
{
    __shared__ __align__(16) ushort hB[64][392];

    const int tid  = threadIdx.x;
    const int wave = tid >> 6, lane = tid & 63;
    const int cu   = lane & 15;
    const int g4   = lane >> 4;
    const int gk8  = g4 << 3;
    const int gr4  = g4 << 2;
    const int t0g  = blockIdx.x * 64;
    const int tok  = t0g + (wave << 4) + cu;   // this lane's token row

    // load 24 values (cols gk8+{0..7}, +32, +64) and LayerNorm in registers
    float vals[24];
    if (CLEAN) {
        const ushort* base = xsrc + tok * 96 + gk8;
        s16x8 r0 = *(const s16x8*)(base);
        s16x8 r1 = *(const s16x8*)(base + 32);
        s16x8 r2 = *(const s16x8*)(base + 64);
        #pragma unroll
        for (int i = 0; i < 8; ++i) {
            vals[i]      = bs2f((ushort)r0[i]);
            vals[8 + i]  = bs2f((ushort)r1[i]);
            vals[16 + i] = bs2f((ushort)r2[i]);
        }
    } else {
        int bb = tok / 50176;
        int tl = tok % 50176;
        #pragma unroll
        for (int s = 0; s < 3; ++s)
            #pragma unroll
            for (int i = 0; i < 8; ++i) {
                int p = tl * 96 + gk8 + s * 32 + i;
                int c = p / 50176, rem = p % 50176;
                int w = rem / 224, h = rem % 224;
                vals[s * 8 + i] = bs2f(xsrc[bb * M_ + c * 50176 + h * 224 + w]);
            }
    }
    float sum = 0.f, sq = 0.f;
    #pragma unroll
    for (int i = 0; i < 24; ++i) { sum += vals[i]; sq += vals[i] * vals[i]; }
    sum += __shfl_xor(sum, 16); sq += __shfl_xor(sq, 16);
    sum += __shfl_xor(sum, 32); sq += __shfl_xor(sq, 32);
    float mu   = sum * (1.0f / 96.0f);
    float rstd = rsqrtf(sq * (1.0f / 96.0f) - mu * mu + 1e-5f);

    s16x8 a0, a1, a2;
    #pragma unroll
    for (int i = 0; i < 8; ++i) {
        int c0 = gk8 + i, c1 = gk8 + 32 + i, c2 = gk8 + 64 + i;
        a0[i] = (short)f2bs((vals[i]      - mu) * rstd * n2g[c0] + n2b[c0]);
        a1[i] = (short)f2bs((vals[8 + i]  - mu) * rstd * n2g[c1] + n2b[c1]);
        a2[i] = (short)f2bs((vals[16 + i] - mu) * rstd * n2g[c2] + n2b[c2]);
    }

    const int tr = (wave << 4) + gr4;
    // fc1 + exact GELU -> hB (own-wave rows)
    #pragma unroll
    for (int nt = 0; nt < 24; ++nt) {
        int nc = (nt << 4) | cu;
        const ushort* bp = wf1 + nc * 96 + gk8;
        s16x8 b0 = *(const s16x8*)(bp);
        s16x8 b1 = *(const s16x8*)(bp + 32);
        s16x8 b2 = *(const s16x8*)(bp + 64);
        f32x4 acc = {0.f, 0.f, 0.f, 0.f};
        acc = mfma16(a0, b0, acc);
        acc = mfma16(a1, b1, acc);
        acc = mfma16(a2, b2, acc);
        float bias = b1v[nc];
        #pragma unroll
        for (int r = 0; r < 4; ++r) {
            float v = acc[r] + bias;
            v = 0.5f * v * (1.0f + erff(v * 0.7071067811865476f));
            hB[tr + r][nc] = f2bs(v);
        }
    }

    // fc2 + residual (own-wave rows; same-wave LDS RAW, no barrier needed)
    {
        const int arr = (wave << 4) | cu;
        s16x8 ha[12];
        #pragma unroll
        for (int ks = 0; ks < 12; ++ks)
            ha[ks] = *(const s16x8*)&hB[arr][ks * 32 + gk8];
        #pragma unroll
        for (int nt = 0; nt < 6; ++nt) {
            int nc = (nt << 4) | cu;
            f32x4 acc = {0.f, 0.f, 0.f, 0.f};
            #pragma unroll
            for (int ks = 0; ks < 12; ++ks) {
                s16x8 bv = *(const s16x8*)&wf2[nc * 384 + ks * 32 + gk8];
                acc = mfma16(ha[ks], bv, acc);
            }
            float bias = b2v[nc];
            #pragma unroll
            for (int r = 0; r < 4; ++r) {
                int G = (t0g + tr + r) * 96 + nc;
                out[G] = bias + acc[r] + bs2f(x1flat[G]);
            }
        }
    }
}

// ---------------------------------------------------------------------------
extern "C" void kernel_launch(void* const* d_in, const int* in_sizes, int n_in,
                              void* d_out, int out_size, void* d_ws, size_t ws_size,
                              hipStream_t stream) {
    const float* x      = (const float*)d_in[0];
    const float* amask  = (const float*)d_in[1];
    const float* n1g    = (const float*)d_in[2];
    const float* n1b    = (const float*)d_in[3];
    const float* qkvw   = (const float*)d_in[4];
    const float* qkvb   = (const float*)d_in[5];
    const float* rpb    = (const float*)d_in[6];
    const float* projw  = (const float*)d_in[7];
    const float* projb  = (const float*)d_in[8];
    const float* n2g    = (const float*)d_in[9];
    const float* n2b    = (const float*)d_in[10];
    const float* w1     = (const float*)d_in[11];
    const float* b1     = (const float*)d_in[12];
    const float* w2     = (const float*)d_in[13];
    const float* b2     = (const float*)d_in[14];

    char* ws = (char*)d_ws;
    ushort* wq  = (ushort*)(ws);            // 27648 el
    ushort* wp  = (ushort*)(ws + 55296);    // 9216 el
    ushort* wf1 = (ushort*)(ws + 73728);    // 36864 el
    ushort* wf2 = (ushort*)(ws + 147456);   // 36864 el
    ushort* x1  = (ushort*)(ws + 262144);   // 38,535,168 el (77.07 MB)
    ushort* x1p = (ushort*)(ws + 77332480); // permuted copy (77.07 MB)
    float* out = (float*)d_out;

    const bool clean = (ws_size >= (size_t)154402816);

    prep_kernel<<<dim3(144), dim3(256), 0, stream>>>(qkvw, projw, w1, w2, wq, wp, wf1, wf2);

    attn_kernel<<<dim3(8192), dim3(256), 0, stream>>>(
        x, amask, n1g, n1b, qkvb, rpb, projb, wq, wp, x1);

    if (clean) {
        transpose_kernel<<<dim3(37632), dim3(256), 0, stream>>>(x1, x1p);
        mlp_kernel<true><<<dim3(6272), dim3(256), 0, stream>>>(
            x1p, x1, n2g, n2b, b1, b2, wf1, wf2, out);
    } else {
        mlp_kernel<false><<<dim3(6272), dim3(256), 0, stream>>>(
            x1, x1, n2g, n2b, b1, b2, wf1, wf2, out);
    }
}

// Round 9
// 757.603 us; speedup vs baseline: 18.9069x; 1.0795x over previous
//
#include <hip/hip_runtime.h>
#include <hip/hip_bf16.h>

// Swin block B=8,C=96,H=W=224,WS=7,SS=3,NH=3,HD=32,N=49(pad 64),MLP_H=384
// fp32 in/out; bf16 MFMA (16x16x32). d_ws: weights | x1 (flat) | x1p (permuted).

typedef __attribute__((ext_vector_type(4))) float f32x4;
typedef __attribute__((ext_vector_type(8))) short s16x8;

constexpr int B_ = 8;
constexpr int M_ = 96 * 224 * 224;   // 4,816,896 per-batch elements

__device__ __forceinline__ ushort f2bs(float f) {
    __hip_bfloat16 h = __float2bfloat16(f);
    ushort u; __builtin_memcpy(&u, &h, 2); return u;
}
__device__ __forceinline__ float bs2f(ushort u) {
    __hip_bfloat16 h; __builtin_memcpy(&h, &u, 2); return __bfloat162float(h);
}
__device__ __forceinline__ f32x4 mfma16(s16x8 a, s16x8 b, f32x4 c) {
    return __builtin_amdgcn_mfma_f32_16x16x32_bf16(a, b, c, 0, 0, 0);
}
// exact-erf GELU via A&S 7.1.26 (abs err 1.5e-7, far below bf16 rounding)
__device__ __forceinline__ float gelu_f(float v) {
    float s  = v * 0.70710678118654752f;
    float as = fabsf(s);
    float t  = __builtin_amdgcn_rcpf(fmaf(0.3275911f, as, 1.0f));
    float p  = fmaf(fmaf(fmaf(fmaf(1.061405429f, t, -1.453152027f), t,
                   1.421413741f), t, -0.284496736f), t, 0.254829592f) * t;
    float y  = 1.0f - p * __expf(-s * s);
    float er = copysignf(y, s);
    return 0.5f * v * (1.0f + er);
}

// ---------------------------------------------------------------------------
// prep: pack transposed bf16 weights.
// ---------------------------------------------------------------------------
__global__ __launch_bounds__(256) void prep_kernel(
    const float* __restrict__ qkvw, const float* __restrict__ projw,
    const float* __restrict__ w1,   const float* __restrict__ w2,
    ushort* __restrict__ wq, ushort* __restrict__ wp,
    ushort* __restrict__ wf1, ushort* __restrict__ wf2)
{
    int i = blockIdx.x * 256 + threadIdx.x;
    if (i < 27648) { int n = i / 96, k = i % 96;  wq[i]  = f2bs(qkvw[k * 288 + n]); }
    if (i < 9216)  { int n = i / 96, k = i % 96;  wp[i]  = f2bs(projw[k * 96 + n]); }
    if (i < 36864) {
        int n = i / 96,  k = i % 96;   wf1[i] = f2bs(w1[k * 384 + n]);
        int n2 = i / 384, k2 = i % 384; wf2[i] = f2bs(w2[k2 * 96 + n2]);
    }
}

// ---------------------------------------------------------------------------
// attn: LN1+shift+window+QKV+MHA+proj+faithful residual. 1 window / block,
// 256 thr (4 waves), 8192 blocks XCD-swizzled. LDS 50.5 KB -> 3 blocks/CU.
// Phases 1/7 use fixed-role threads: (t, c-group) per thread, c-loop is pure
// pointer increments (no div/mod in the loop).
// ---------------------------------------------------------------------------
__global__ __launch_bounds__(256) void attn_kernel(
    const float* __restrict__ x,
    const float* __restrict__ amask,
    const float* __restrict__ n1g, const float* __restrict__ n1b,
    const float* __restrict__ qkvb,
    const float* __restrict__ rpb,
    const float* __restrict__ projb,
    const ushort* __restrict__ wq, const ushort* __restrict__ wp,
    ushort* __restrict__ x1)
{
    __shared__ __align__(16) ushort T[64][104];    // tokens -> q -> proj-out
    __shared__ __align__(16) ushort K[64][104];    // k
    __shared__ __align__(16) ushort vT[96][72];    // [d][t]
    __shared__ __align__(16) ushort Pws[4][16][72];// per-wave P slab
    __shared__ float rpbs[512];

    const int tid  = threadIdx.x;
    const int wave = tid >> 6, lane = tid & 63;
    const int cu   = lane & 15;
    const int g4   = lane >> 4;
    const int gk8  = g4 << 3;
    const int gr4  = g4 << 2;

    // XCD swizzle: consecutive windows (adjacent ww) on same XCD L2
    const int blk = (blockIdx.x & 7) * 1024 + (blockIdx.x >> 3);
    const int b   = blk >> 10;
    const int wi  = blk & 1023;
    const int wh  = wi >> 5, ww = wi & 31;
    const int bM  = b * M_;
    const bool need_mask = (wh == 31) || (ww == 31);

    for (int i = tid; i < 507; i += 256) rpbs[i] = rpb[i];

    // fixed-role decomposition for phases 1/7: thread = token t + c-group g
    const int t49 = tid % 49;            // token (valid when tid < 245)
    const int g5  = tid / 49;            // c-group 0..4
    int hh_s = 0, wc_s = 0;
    if (tid < 245) {
        int i = t49 / 7, j = t49 % 7;
        hh_s = wh * 7 + i + 3; if (hh_s >= 224) hh_s -= 224;
        wc_s = ww * 7 + j + 3; if (wc_s >= 224) wc_s -= 224;
    }

    // phase 1: load shifted window; c-loop = pointer increments
    if (tid < 245) {
        const float* xp = x + bM + g5 * 50176 + hh_s * 224 + wc_s;
        ushort* dT = &T[t49][g5];
        for (int c = g5; c < 96; c += 5) {
            *dT = f2bs(*xp);
            xp += 5 * 50176; dT += 5;
        }
    }
    // zero pad rows 49..63 (uint-wide; T rows contiguous, 4B-aligned)
    {
        uint* z = (uint*)&T[49][0];
        for (int i = tid; i < 780; i += 256) z[i] = 0u;
    }
    __syncthreads();   // B1

    // LN1: 4 lanes per token (t<49)
    if (tid < 196) {
        int t = tid >> 2, s = tid & 3;
        float sum = 0.f, sq = 0.f;
        float vv[24];
        #pragma unroll
        for (int i = 0; i < 24; ++i) {
            vv[i] = bs2f(T[t][s * 24 + i]);
            sum += vv[i]; sq += vv[i] * vv[i];
        }
        sum += __shfl_xor(sum, 1); sq += __shfl_xor(sq, 1);
        sum += __shfl_xor(sum, 2); sq += __shfl_xor(sq, 2);
        float mu   = sum * (1.0f / 96.0f);
        float rstd = rsqrtf(sq * (1.0f / 96.0f) - mu * mu + 1e-5f);
        #pragma unroll
        for (int i = 0; i < 24; ++i) {
            int c = s * 24 + i;
            T[t][c] = f2bs((vv[i] - mu) * rstd * n1g[c] + n1b[c]);
        }
    }
    __syncthreads();   // B2

    const int ar = (wave << 4) | cu;
    const int tr = (wave << 4) + gr4;

    // qkv GEMM: wave owns M-tile; q -> regs, k -> K LDS, v -> vT LDS
    {
        s16x8 a0 = *(const s16x8*)&T[ar][gk8];
        s16x8 a1 = *(const s16x8*)&T[ar][32 + gk8];
        s16x8 a2 = *(const s16x8*)&T[ar][64 + gk8];
        f32x4 qreg[6];
        #pragma unroll
        for (int nt = 0; nt < 18; ++nt) {
            int nc = (nt << 4) | cu;
            const ushort* bp = wq + nc * 96 + gk8;
            s16x8 b0 = *(const s16x8*)(bp);
            s16x8 b1 = *(const s16x8*)(bp + 32);
            s16x8 b2 = *(const s16x8*)(bp + 64);
            f32x4 acc = {0.f, 0.f, 0.f, 0.f};
            acc = mfma16(a0, b0, acc);
            acc = mfma16(a1, b1, acc);
            acc = mfma16(a2, b2, acc);
            float bias = qkvb[nc];
            if (nt < 6) {
                #pragma unroll
                for (int r = 0; r < 4; ++r)
                    qreg[nt][r] = (acc[r] + bias) * 0.17677669529663689f;
            } else if (nc < 192) {
                #pragma unroll
                for (int r = 0; r < 4; ++r) K[tr + r][nc - 96] = f2bs(acc[r] + bias);
            } else {
                int d = nc - 192;
                ushort4 pk;
                pk.x = f2bs(acc[0] + bias); pk.y = f2bs(acc[1] + bias);
                pk.z = f2bs(acc[2] + bias); pk.w = f2bs(acc[3] + bias);
                *(ushort4*)&vT[d][tr] = pk;
            }
        }
        // write q into T (own rows; token data fully consumed by this wave)
        #pragma unroll
        for (int qn = 0; qn < 6; ++qn)
            #pragma unroll
            for (int r = 0; r < 4; ++r)
                T[tr + r][(qn << 4) | cu] = f2bs(qreg[qn][r]);
    }
    __syncthreads();   // B3

    // per-lane loop-invariant rpb/mask helpers
    int u7d[4], u7m[4];
    #pragma unroll
    for (int ut = 0; ut < 4; ++ut) {
        int u = (ut << 4) | cu;
        u7d[ut] = u / 7; u7m[ut] = u % 7;
    }

    // tasks: (hh=0..2, tt=wave). O accumulated in registers.
    f32x4 osc[3][2];
    #pragma unroll
    for (int it = 0; it < 3; ++it) {
        const int hh = it;
        const int t0r = tr;

        s16x8 aq = *(const s16x8*)&T[ar][(hh << 5) + gk8];
        f32x4 sa[4];
        #pragma unroll
        for (int ut = 0; ut < 4; ++ut) {
            s16x8 bk = *(const s16x8*)&K[(ut << 4) | cu][(hh << 5) + gk8];
            f32x4 z = {0.f, 0.f, 0.f, 0.f};
            sa[ut] = mfma16(aq, bk, z);
        }
        #pragma unroll
        for (int ut = 0; ut < 4; ++ut) {
            int u = (ut << 4) | cu;
            #pragma unroll
            for (int r = 0; r < 4; ++r) {
                int t = t0r + r;
                float s = sa[ut][r];
                if (t < 49 && u < 49) {
                    int dr = t / 7 - u7d[ut] + 6, dc = t % 7 - u7m[ut] + 6;
                    s += rpbs[(dr * 13 + dc) * 3 + hh];
                    if (need_mask) s += amask[(wi * 49 + t) * 49 + u];
                } else if (u >= 49) {
                    s = -1e30f;
                }
                sa[ut][r] = s;
            }
        }
        float inv[4];
        #pragma unroll
        for (int r = 0; r < 4; ++r) {
            float m = fmaxf(fmaxf(sa[0][r], sa[1][r]), fmaxf(sa[2][r], sa[3][r]));
            m = fmaxf(m, __shfl_xor(m, 1)); m = fmaxf(m, __shfl_xor(m, 2));
            m = fmaxf(m, __shfl_xor(m, 4)); m = fmaxf(m, __shfl_xor(m, 8));
            float e0 = __expf(sa[0][r] - m), e1 = __expf(sa[1][r] - m);
            float e2 = __expf(sa[2][r] - m), e3 = __expf(sa[3][r] - m);
            sa[0][r] = e0; sa[1][r] = e1; sa[2][r] = e2; sa[3][r] = e3;
            float s = (e0 + e1) + (e2 + e3);
            s += __shfl_xor(s, 1); s += __shfl_xor(s, 2);
            s += __shfl_xor(s, 4); s += __shfl_xor(s, 8);
            inv[r] = 1.0f / s;
        }
        #pragma unroll
        for (int ut = 0; ut < 4; ++ut) {
            int u = (ut << 4) | cu;
            #pragma unroll
            for (int r = 0; r < 4; ++r) Pws[wave][gr4 + r][u] = f2bs(sa[ut][r]);
        }
        s16x8 pa0 = *(const s16x8*)&Pws[wave][cu][gk8];
        s16x8 pa1 = *(const s16x8*)&Pws[wave][cu][32 + gk8];
        #pragma unroll
        for (int nt = 0; nt < 2; ++nt) {
            int d = (hh << 5) + (nt << 4) + cu;
            s16x8 bv0 = *(const s16x8*)&vT[d][gk8];
            s16x8 bv1 = *(const s16x8*)&vT[d][32 + gk8];
            f32x4 acc = {0.f, 0.f, 0.f, 0.f};
            acc = mfma16(pa0, bv0, acc);
            acc = mfma16(pa1, bv1, acc);
            #pragma unroll
            for (int r = 0; r < 4; ++r) osc[it][nt][r] = acc[r] * inv[r];
        }
    }
    __syncthreads();   // B4: all K reads complete

    // O -> K (own rows)
    #pragma unroll
    for (int it = 0; it < 3; ++it)
        #pragma unroll
        for (int nt = 0; nt < 2; ++nt)
            #pragma unroll
            for (int r = 0; r < 4; ++r)
                K[tr + r][(it << 5) + (nt << 4) + cu] = f2bs(osc[it][nt][r]);

    // proj: A from K (own rows), out -> T (own rows)
    {
        s16x8 a0 = *(const s16x8*)&K[ar][gk8];
        s16x8 a1 = *(const s16x8*)&K[ar][32 + gk8];
        s16x8 a2 = *(const s16x8*)&K[ar][64 + gk8];
        #pragma unroll
        for (int nt = 0; nt < 6; ++nt) {
            int nc = (nt << 4) | cu;
            const ushort* bp = wp + nc * 96 + gk8;
            s16x8 b0 = *(const s16x8*)(bp);
            s16x8 b1 = *(const s16x8*)(bp + 32);
            s16x8 b2 = *(const s16x8*)(bp + 64);
            f32x4 acc = {0.f, 0.f, 0.f, 0.f};
            acc = mfma16(a0, b0, acc);
            acc = mfma16(a1, b1, acc);
            acc = mfma16(a2, b2, acc);
            float bias = projb[nc];
            #pragma unroll
            for (int r = 0; r < 4; ++r) T[tr + r][nc] = f2bs(acc[r] + bias);
        }
    }
    __syncthreads();   // B5

    // phase 7: faithful-permute residual; c-loop = pointer increments
    if (tid < 245) {
        const int base = bM + (hh_s * 96 + g5) * 224 + wc_s;
        const float* xp = x + base;
        ushort* dx = x1 + base;
        const ushort* Tp = &T[t49][g5];
        for (int c = g5; c < 96; c += 5) {
            *dx = f2bs(*xp + bs2f(*Tp));
            xp += 5 * 224; dx += 5 * 224; Tp += 5;
        }
    }
}

// ---------------------------------------------------------------------------
// transpose: per (b,c) slab, x1p[base + w*224 + h] = x1[base + h*224 + w].
// 32x32 tiles: 768 slabs * 49 tiles = 37632 blocks x 256.
// ---------------------------------------------------------------------------
__global__ __launch_bounds__(256) void transpose_kernel(
    const ushort* __restrict__ x1, ushort* __restrict__ x1p)
{
    __shared__ ushort tile[32][36];
    const int id      = blockIdx.x;
    const int tile_id = id % 49;
    const int slab    = id / 49;          // b*96 + c
    const int h0 = (tile_id / 7) * 32;
    const int w0 = (tile_id % 7) * 32;
    const ushort* src = x1  + slab * 50176;
    ushort*       dst = x1p + slab * 50176;

    const int i = threadIdx.x >> 3;       // 0..31
    const int j = (threadIdx.x & 7) * 4;  // 0,4,...,28

    *(ushort4*)&tile[i][j] = *(const ushort4*)&src[(h0 + i) * 224 + w0 + j];
    __syncthreads();
    ushort4 v;
    v.x = tile[j][i]; v.y = tile[j + 1][i]; v.z = tile[j + 2][i]; v.w = tile[j + 3][i];
    *(ushort4*)&dst[(w0 + i) * 224 + h0 + j] = v;
}

// ---------------------------------------------------------------------------
// MLP: reg-LN -> interleaved fc1+GELU / fc2 (12 chunk-steps, per-wave 5KB
// slab, fc2 accumulators in registers) -> residual. 64 tokens / block,
// 256 thr, 6272 blocks. LDS 5.1 KB -> VGPR-capped occupancy (~5-6 blk/CU).
// ---------------------------------------------------------------------------
template <bool CLEAN>
__global__ __launch_bounds__(256) void mlp_kernel(
    const ushort* __restrict__ xsrc,
    const ushort* __restrict__ x1flat,
    const float* __restrict__ n2g, const float* __restrict__ n2b,
    const float* __restrict__ b1v, const float* __restrict__ b2v,
    const ushort* __restrict__ wf1, const ushort* __restrict__ wf2,
    float* __restrict__ out)
{
    __shared__ __align__(16) ushort hS[4][16][40];   // per-wave 16x32 chunk (+8 pad)

    const int tid  = threadIdx.x;
    const int wave = tid >> 6, lane = tid & 63;
    const int cu   = lane & 15;
    const int g4   = lane >> 4;
    const int gk8  = g4 << 3;
    const int gr4  = g4 << 2;
    const int t0g  = blockIdx.x * 64;
    const int tok  = t0g + (wave << 4) + cu;   // this lane's token row

    // load 24 values (cols gk8+{0..7}, +32, +64) and LayerNorm in registers
    float vals[24];
    if (CLEAN) {
        const ushort* base = xsrc + tok * 96 + gk8;
        s16x8 r0 = *(const s16x8*)(base);
        s16x8 r1 = *(const s16x8*)(base + 32);
        s16x8 r2 = *(const s16x8*)(base + 64);
        #pragma unroll
        for (int i = 0; i < 8; ++i) {
            vals[i]      = bs2f((ushort)r0[i]);
            vals[8 + i]  = bs2f((ushort)r1[i]);
            vals[16 + i] = bs2f((ushort)r2[i]);
        }
    } else {
        int bb = tok / 50176;
        int tl = tok % 50176;
        #pragma unroll
        for (int s = 0; s < 3; ++s)
            #pragma unroll
            for (int i = 0; i < 8; ++i) {
                int p = tl * 96 + gk8 + s * 32 + i;
                int c = p / 50176, rem = p % 50176;
                int w = rem / 224, h = rem % 224;
                vals[s * 8 + i] = bs2f(xsrc[bb * M_ + c * 50176 + h * 224 + w]);
            }
    }
    float sum = 0.f, sq = 0.f;
    #pragma unroll
    for (int i = 0; i < 24; ++i) { sum += vals[i]; sq += vals[i] * vals[i]; }
    sum += __shfl_xor(sum, 16); sq += __shfl_xor(sq, 16);
    sum += __shfl_xor(sum, 32); sq += __shfl_xor(sq, 32);
    float mu   = sum * (1.0f / 96.0f);
    float rstd = rsqrtf(sq * (1.0f / 96.0f) - mu * mu + 1e-5f);

    s16x8 a0, a1, a2;
    #pragma unroll
    for (int i = 0; i < 8; ++i) {
        int c0 = gk8 + i, c1 = gk8 + 32 + i, c2 = gk8 + 64 + i;
        a0[i] = (short)f2bs((vals[i]      - mu) * rstd * n2g[c0] + n2b[c0]);
        a1[i] = (short)f2bs((vals[8 + i]  - mu) * rstd * n2g[c1] + n2b[c1]);
        a2[i] = (short)f2bs((vals[16 + i] - mu) * rstd * n2g[c2] + n2b[c2]);
    }

    // 12 steps: fc1 for h-cols 32s..32s+31 -> slab -> fc2 partial (ks = s)
    f32x4 oacc[6];
    #pragma unroll
    for (int nt2 = 0; nt2 < 6; ++nt2) oacc[nt2] = (f32x4){0.f, 0.f, 0.f, 0.f};

    for (int s = 0; s < 12; ++s) {
        #pragma unroll
        for (int half = 0; half < 2; ++half) {
            int nc = ((2 * s + half) << 4) | cu;
            const ushort* bp = wf1 + nc * 96 + gk8;
            s16x8 b0 = *(const s16x8*)(bp);
            s16x8 b1 = *(const s16x8*)(bp + 32);
            s16x8 b2 = *(const s16x8*)(bp + 64);
            f32x4 acc = {0.f, 0.f, 0.f, 0.f};
            acc = mfma16(a0, b0, acc);
            acc = mfma16(a1, b1, acc);
            acc = mfma16(a2, b2, acc);
            float bias = b1v[nc];
            #pragma unroll
            for (int r = 0; r < 4; ++r)
                hS[wave][gr4 + r][(half << 4) | cu] = f2bs(gelu_f(acc[r] + bias));
        }
        // same-wave DS ordering makes the slab visible without a barrier
        s16x8 ha = *(const s16x8*)&hS[wave][cu][gk8];
        #pragma unroll
        for (int nt2 = 0; nt2 < 6; ++nt2) {
            int nc2 = (nt2 << 4) | cu;
            s16x8 bv = *(const s16x8*)&wf2[nc2 * 384 + s * 32 + gk8];
            oacc[nt2] = mfma16(ha, bv, oacc[nt2]);
        }
    }

    // epilogue: bias + residual at un-permuted flat index
    const int tr = (wave << 4) + gr4;
    #pragma unroll
    for (int nt2 = 0; nt2 < 6; ++nt2) {
        int nc2 = (nt2 << 4) | cu;
        float bias = b2v[nc2];
        #pragma unroll
        for (int r = 0; r < 4; ++r) {
            int G = (t0g + tr + r) * 96 + nc2;
            out[G] = bias + oacc[nt2][r] + bs2f(x1flat[G]);
        }
    }
}

// ---------------------------------------------------------------------------
extern "C" void kernel_launch(void* const* d_in, const int* in_sizes, int n_in,
                              void* d_out, int out_size, void* d_ws, size_t ws_size,
                              hipStream_t stream) {
    const float* x      = (const float*)d_in[0];
    const float* amask  = (const float*)d_in[1];
    const float* n1g    = (const float*)d_in[2];
    const float* n1b    = (const float*)d_in[3];
    const float* qkvw   = (const float*)d_in[4];
    const float* qkvb   = (const float*)d_in[5];
    const float* rpb    = (const float*)d_in[6];
    const float* projw  = (const float*)d_in[7];
    const float* projb  = (const float*)d_in[8];
    const float* n2g    = (const float*)d_in[9];
    const float* n2b    = (const float*)d_in[10];
    const float* w1     = (const float*)d_in[11];
    const float* b1     = (const float*)d_in[12];
    const float* w2     = (const float*)d_in[13];
    const float* b2     = (const float*)d_in[14];

    char* ws = (char*)d_ws;
    ushort* wq  = (ushort*)(ws);            // 27648 el
    ushort* wp  = (ushort*)(ws + 55296);    // 9216 el
    ushort* wf1 = (ushort*)(ws + 73728);    // 36864 el
    ushort* wf2 = (ushort*)(ws + 147456);   // 36864 el
    ushort* x1  = (ushort*)(ws + 262144);   // 38,535,168 el (77.07 MB)
    ushort* x1p = (ushort*)(ws + 77332480); // permuted copy (77.07 MB)
    float* out = (float*)d_out;

    const bool clean = (ws_size >= (size_t)154402816);

    prep_kernel<<<dim3(144), dim3(256), 0, stream>>>(qkvw, projw, w1, w2, wq, wp, wf1, wf2);

    attn_kernel<<<dim3(8192), dim3(256), 0, stream>>>(
        x, amask, n1g, n1b, qkvb, rpb, projb, wq, wp, x1);

    if (clean) {
        transpose_kernel<<<dim3(37632), dim3(256), 0, stream>>>(x1, x1p);
        mlp_kernel<true><<<dim3(6272), dim3(256), 0, stream>>>(
            x1p, x1, n2g, n2b, b1, b2, wf1, wf2, out);
    } else {
        mlp_kernel<false><<<dim3(6272), dim3(256), 0, stream>>>(
            x1, x1, n2g, n2b, b1, b2, wf1, wf2, out);
    }
}

// Round 10
// 646.211 us; speedup vs baseline: 22.1661x; 1.1724x over previous
//
#include <hip/hip_runtime.h>
#include <hip/hip_bf16.h>

// Swin block B=8,C=96,H=W=224,WS=7,SS=3,NH=3,HD=32,N=49(pad 64),MLP_H=384
// fp32 in/out; bf16 MFMA (16x16x32). d_ws: weights | x1 (flat) | x1p (permuted).

typedef __attribute__((ext_vector_type(4))) float f32x4;
typedef __attribute__((ext_vector_type(8))) short s16x8;

constexpr int B_ = 8;
constexpr int M_ = 96 * 224 * 224;   // 4,816,896 per-batch elements

__device__ __forceinline__ ushort f2bs(float f) {
    __hip_bfloat16 h = __float2bfloat16(f);
    ushort u; __builtin_memcpy(&u, &h, 2); return u;
}
__device__ __forceinline__ float bs2f(ushort u) {
    __hip_bfloat16 h; __builtin_memcpy(&h, &u, 2); return __bfloat162float(h);
}
__device__ __forceinline__ f32x4 mfma16(s16x8 a, s16x8 b, f32x4 c) {
    return __builtin_amdgcn_mfma_f32_16x16x32_bf16(a, b, c, 0, 0, 0);
}
// exact-erf GELU via A&S 7.1.26 (abs err 1.5e-7, far below bf16 rounding)
__device__ __forceinline__ float gelu_f(float v) {
    float s  = v * 0.70710678118654752f;
    float as = fabsf(s);
    float t  = __builtin_amdgcn_rcpf(fmaf(0.3275911f, as, 1.0f));
    float p  = fmaf(fmaf(fmaf(fmaf(1.061405429f, t, -1.453152027f), t,
                   1.421413741f), t, -0.284496736f), t, 0.254829592f) * t;
    float y  = 1.0f - p * __expf(-s * s);
    float er = copysignf(y, s);
    return 0.5f * v * (1.0f + er);
}

// ---------------------------------------------------------------------------
// prep: pack transposed bf16 weights.
// ---------------------------------------------------------------------------
__global__ __launch_bounds__(256) void prep_kernel(
    const float* __restrict__ qkvw, const float* __restrict__ projw,
    const float* __restrict__ w1,   const float* __restrict__ w2,
    ushort* __restrict__ wq, ushort* __restrict__ wp,
    ushort* __restrict__ wf1, ushort* __restrict__ wf2)
{
    int i = blockIdx.x * 256 + threadIdx.x;
    if (i < 27648) { int n = i / 96, k = i % 96;  wq[i]  = f2bs(qkvw[k * 288 + n]); }
    if (i < 9216)  { int n = i / 96, k = i % 96;  wp[i]  = f2bs(projw[k * 96 + n]); }
    if (i < 36864) {
        int n = i / 96,  k = i % 96;   wf1[i] = f2bs(w1[k * 384 + n]);
        int n2 = i / 384, k2 = i % 384; wf2[i] = f2bs(w2[k2 * 96 + n2]);
    }
}

// ---------------------------------------------------------------------------
// attn: LN1+shift+window+QKV+MHA+proj+faithful residual. 1 window / block,
// 256 thr (4 waves), 8192 blocks XCD-swizzled. LDS 50.5 KB -> 3 blocks/CU.
// (unchanged from round 9)
// ---------------------------------------------------------------------------
__global__ __launch_bounds__(256) void attn_kernel(
    const float* __restrict__ x,
    const float* __restrict__ amask,
    const float* __restrict__ n1g, const float* __restrict__ n1b,
    const float* __restrict__ qkvb,
    const float* __restrict__ rpb,
    const float* __restrict__ projb,
    const ushort* __restrict__ wq, const ushort* __restrict__ wp,
    ushort* __restrict__ x1)
{
    __shared__ __align__(16) ushort T[64][104];    // tokens -> q -> proj-out
    __shared__ __align__(16) ushort K[64][104];    // k
    __shared__ __align__(16) ushort vT[96][72];    // [d][t]
    __shared__ __align__(16) ushort Pws[4][16][72];// per-wave P slab
    __shared__ float rpbs[512];

    const int tid  = threadIdx.x;
    const int wave = tid >> 6, lane = tid & 63;
    const int cu   = lane & 15;
    const int g4   = lane >> 4;
    const int gk8  = g4 << 3;
    const int gr4  = g4 << 2;

    const int blk = (blockIdx.x & 7) * 1024 + (blockIdx.x >> 3);
    const int b   = blk >> 10;
    const int wi  = blk & 1023;
    const int wh  = wi >> 5, ww = wi & 31;
    const int bM  = b * M_;
    const bool need_mask = (wh == 31) || (ww == 31);

    for (int i = tid; i < 507; i += 256) rpbs[i] = rpb[i];

    const int t49 = tid % 49;
    const int g5  = tid / 49;
    int hh_s = 0, wc_s = 0;
    if (tid < 245) {
        int i = t49 / 7, j = t49 % 7;
        hh_s = wh * 7 + i + 3; if (hh_s >= 224) hh_s -= 224;
        wc_s = ww * 7 + j + 3; if (wc_s >= 224) wc_s -= 224;
    }

    if (tid < 245) {
        const float* xp = x + bM + g5 * 50176 + hh_s * 224 + wc_s;
        ushort* dT = &T[t49][g5];
        for (int c = g5; c < 96; c += 5) {
            *dT = f2bs(*xp);
            xp += 5 * 50176; dT += 5;
        }
    }
    {
        uint* z = (uint*)&T[49][0];
        for (int i = tid; i < 780; i += 256) z[i] = 0u;
    }
    __syncthreads();   // B1

    if (tid < 196) {
        int t = tid >> 2, s = tid & 3;
        float sum = 0.f, sq = 0.f;
        float vv[24];
        #pragma unroll
        for (int i = 0; i < 24; ++i) {
            vv[i] = bs2f(T[t][s * 24 + i]);
            sum += vv[i]; sq += vv[i] * vv[i];
        }
        sum += __shfl_xor(sum, 1); sq += __shfl_xor(sq, 1);
        sum += __shfl_xor(sum, 2); sq += __shfl_xor(sq, 2);
        float mu   = sum * (1.0f / 96.0f);
        float rstd = rsqrtf(sq * (1.0f / 96.0f) - mu * mu + 1e-5f);
        #pragma unroll
        for (int i = 0; i < 24; ++i) {
            int c = s * 24 + i;
            T[t][c] = f2bs((vv[i] - mu) * rstd * n1g[c] + n1b[c]);
        }
    }
    __syncthreads();   // B2

    const int ar = (wave << 4) | cu;
    const int tr = (wave << 4) + gr4;

    {
        s16x8 a0 = *(const s16x8*)&T[ar][gk8];
        s16x8 a1 = *(const s16x8*)&T[ar][32 + gk8];
        s16x8 a2 = *(const s16x8*)&T[ar][64 + gk8];
        f32x4 qreg[6];
        #pragma unroll
        for (int nt = 0; nt < 18; ++nt) {
            int nc = (nt << 4) | cu;
            const ushort* bp = wq + nc * 96 + gk8;
            s16x8 b0 = *(const s16x8*)(bp);
            s16x8 b1 = *(const s16x8*)(bp + 32);
            s16x8 b2 = *(const s16x8*)(bp + 64);
            f32x4 acc = {0.f, 0.f, 0.f, 0.f};
            acc = mfma16(a0, b0, acc);
            acc = mfma16(a1, b1, acc);
            acc = mfma16(a2, b2, acc);
            float bias = qkvb[nc];
            if (nt < 6) {
                #pragma unroll
                for (int r = 0; r < 4; ++r)
                    qreg[nt][r] = (acc[r] + bias) * 0.17677669529663689f;
            } else if (nc < 192) {
                #pragma unroll
                for (int r = 0; r < 4; ++r) K[tr + r][nc - 96] = f2bs(acc[r] + bias);
            } else {
                int d = nc - 192;
                ushort4 pk;
                pk.x = f2bs(acc[0] + bias); pk.y = f2bs(acc[1] + bias);
                pk.z = f2bs(acc[2] + bias); pk.w = f2bs(acc[3] + bias);
                *(ushort4*)&vT[d][tr] = pk;
            }
        }
        #pragma unroll
        for (int qn = 0; qn < 6; ++qn)
            #pragma unroll
            for (int r = 0; r < 4; ++r)
                T[tr + r][(qn << 4) | cu] = f2bs(qreg[qn][r]);
    }
    __syncthreads();   // B3

    int u7d[4], u7m[4];
    #pragma unroll
    for (int ut = 0; ut < 4; ++ut) {
        int u = (ut << 4) | cu;
        u7d[ut] = u / 7; u7m[ut] = u % 7;
    }

    f32x4 osc[3][2];
    #pragma unroll
    for (int it = 0; it < 3; ++it) {
        const int hh = it;
        const int t0r = tr;

        s16x8 aq = *(const s16x8*)&T[ar][(hh << 5) + gk8];
        f32x4 sa[4];
        #pragma unroll
        for (int ut = 0; ut < 4; ++ut) {
            s16x8 bk = *(const s16x8*)&K[(ut << 4) | cu][(hh << 5) + gk8];
            f32x4 z = {0.f, 0.f, 0.f, 0.f};
            sa[ut] = mfma16(aq, bk, z);
        }
        #pragma unroll
        for (int ut = 0; ut < 4; ++ut) {
            int u = (ut << 4) | cu;
            #pragma unroll
            for (int r = 0; r < 4; ++r) {
                int t = t0r + r;
                float s = sa[ut][r];
                if (t < 49 && u < 49) {
                    int dr = t / 7 - u7d[ut] + 6, dc = t % 7 - u7m[ut] + 6;
                    s += rpbs[(dr * 13 + dc) * 3 + hh];
                    if (need_mask) s += amask[(wi * 49 + t) * 49 + u];
                } else if (u >= 49) {
                    s = -1e30f;
                }
                sa[ut][r] = s;
            }
        }
        float inv[4];
        #pragma unroll
        for (int r = 0; r < 4; ++r) {
            float m = fmaxf(fmaxf(sa[0][r], sa[1][r]), fmaxf(sa[2][r], sa[3][r]));
            m = fmaxf(m, __shfl_xor(m, 1)); m = fmaxf(m, __shfl_xor(m, 2));
            m = fmaxf(m, __shfl_xor(m, 4)); m = fmaxf(m, __shfl_xor(m, 8));
            float e0 = __expf(sa[0][r] - m), e1 = __expf(sa[1][r] - m);
            float e2 = __expf(sa[2][r] - m), e3 = __expf(sa[3][r] - m);
            sa[0][r] = e0; sa[1][r] = e1; sa[2][r] = e2; sa[3][r] = e3;
            float s = (e0 + e1) + (e2 + e3);
            s += __shfl_xor(s, 1); s += __shfl_xor(s, 2);
            s += __shfl_xor(s, 4); s += __shfl_xor(s, 8);
            inv[r] = 1.0f / s;
        }
        #pragma unroll
        for (int ut = 0; ut < 4; ++ut) {
            int u = (ut << 4) | cu;
            #pragma unroll
            for (int r = 0; r < 4; ++r) Pws[wave][gr4 + r][u] = f2bs(sa[ut][r]);
        }
        s16x8 pa0 = *(const s16x8*)&Pws[wave][cu][gk8];
        s16x8 pa1 = *(const s16x8*)&Pws[wave][cu][32 + gk8];
        #pragma unroll
        for (int nt = 0; nt < 2; ++nt) {
            int d = (hh << 5) + (nt << 4) + cu;
            s16x8 bv0 = *(const s16x8*)&vT[d][gk8];
            s16x8 bv1 = *(const s16x8*)&vT[d][32 + gk8];
            f32x4 acc = {0.f, 0.f, 0.f, 0.f};
            acc = mfma16(pa0, bv0, acc);
            acc = mfma16(pa1, bv1, acc);
            #pragma unroll
            for (int r = 0; r < 4; ++r) osc[it][nt][r] = acc[r] * inv[r];
        }
    }
    __syncthreads();   // B4

    #pragma unroll
    for (int it = 0; it < 3; ++it)
        #pragma unroll
        for (int nt = 0; nt < 2; ++nt)
            #pragma unroll
            for (int r = 0; r < 4; ++r)
                K[tr + r][(it << 5) + (nt << 4) + cu] = f2bs(osc[it][nt][r]);

    {
        s16x8 a0 = *(const s16x8*)&K[ar][gk8];
        s16x8 a1 = *(const s16x8*)&K[ar][32 + gk8];
        s16x8 a2 = *(const s16x8*)&K[ar][64 + gk8];
        #pragma unroll
        for (int nt = 0; nt < 6; ++nt) {
            int nc = (nt << 4) | cu;
            const ushort* bp = wp + nc * 96 + gk8;
            s16x8 b0 = *(const s16x8*)(bp);
            s16x8 b1 = *(const s16x8*)(bp + 32);
            s16x8 b2 = *(const s16x8*)(bp + 64);
            f32x4 acc = {0.f, 0.f, 0.f, 0.f};
            acc = mfma16(a0, b0, acc);
            acc = mfma16(a1, b1, acc);
            acc = mfma16(a2, b2, acc);
            float bias = projb[nc];
            #pragma unroll
            for (int r = 0; r < 4; ++r) T[tr + r][nc] = f2bs(acc[r] + bias);
        }
    }
    __syncthreads();   // B5

    if (tid < 245) {
        const int base = bM + (hh_s * 96 + g5) * 224 + wc_s;
        const float* xp = x + base;
        ushort* dx = x1 + base;
        const ushort* Tp = &T[t49][g5];
        for (int c = g5; c < 96; c += 5) {
            *dx = f2bs(*xp + bs2f(*Tp));
            xp += 5 * 224; dx += 5 * 224; Tp += 5;
        }
    }
}

// ---------------------------------------------------------------------------
// transpose: per (b,c) slab, x1p[base + w*224 + h] = x1[base + h*224 + w].
// ---------------------------------------------------------------------------
__global__ __launch_bounds__(256) void transpose_kernel(
    const ushort* __restrict__ x1, ushort* __restrict__ x1p)
{
    __shared__ ushort tile[32][36];
    const int id      = blockIdx.x;
    const int tile_id = id % 49;
    const int slab    = id / 49;          // b*96 + c
    const int h0 = (tile_id / 7) * 32;
    const int w0 = (tile_id % 7) * 32;
    const ushort* src = x1  + slab * 50176;
    ushort*       dst = x1p + slab * 50176;

    const int i = threadIdx.x >> 3;
    const int j = (threadIdx.x & 7) * 4;

    *(ushort4*)&tile[i][j] = *(const ushort4*)&src[(h0 + i) * 224 + w0 + j];
    __syncthreads();
    ushort4 v;
    v.x = tile[j][i]; v.y = tile[j + 1][i]; v.z = tile[j + 2][i]; v.w = tile[j + 3][i];
    *(ushort4*)&dst[(w0 + i) * 224 + h0 + j] = v;
}

// ---------------------------------------------------------------------------
// load + LN for one 16-token set; outputs packed bf16 A-frags.
// ---------------------------------------------------------------------------
template <bool CLEAN>
__device__ __forceinline__ void ln_token(
    const ushort* __restrict__ xsrc, int tok, int gk8,
    const float* __restrict__ n2g, const float* __restrict__ n2b,
    s16x8& a0, s16x8& a1, s16x8& a2)
{
    float vals[24];
    if (CLEAN) {
        const ushort* base = xsrc + tok * 96 + gk8;
        s16x8 r0 = *(const s16x8*)(base);
        s16x8 r1 = *(const s16x8*)(base + 32);
        s16x8 r2 = *(const s16x8*)(base + 64);
        #pragma unroll
        for (int i = 0; i < 8; ++i) {
            vals[i]      = bs2f((ushort)r0[i]);
            vals[8 + i]  = bs2f((ushort)r1[i]);
            vals[16 + i] = bs2f((ushort)r2[i]);
        }
    } else {
        int bb = tok / 50176;
        int tl = tok % 50176;
        #pragma unroll
        for (int s = 0; s < 3; ++s)
            #pragma unroll
            for (int i = 0; i < 8; ++i) {
                int p = tl * 96 + gk8 + s * 32 + i;
                int c = p / 50176, rem = p % 50176;
                int w = rem / 224, h = rem % 224;
                vals[s * 8 + i] = bs2f(xsrc[bb * M_ + c * 50176 + h * 224 + w]);
            }
    }
    float sum = 0.f, sq = 0.f;
    #pragma unroll
    for (int i = 0; i < 24; ++i) { sum += vals[i]; sq += vals[i] * vals[i]; }
    sum += __shfl_xor(sum, 16); sq += __shfl_xor(sq, 16);
    sum += __shfl_xor(sum, 32); sq += __shfl_xor(sq, 32);
    float mu   = sum * (1.0f / 96.0f);
    float rstd = rsqrtf(sq * (1.0f / 96.0f) - mu * mu + 1e-5f);
    #pragma unroll
    for (int i = 0; i < 8; ++i) {
        int c0 = gk8 + i, c1 = gk8 + 32 + i, c2 = gk8 + 64 + i;
        a0[i] = (short)f2bs((vals[i]      - mu) * rstd * n2g[c0] + n2b[c0]);
        a1[i] = (short)f2bs((vals[8 + i]  - mu) * rstd * n2g[c1] + n2b[c1]);
        a2[i] = (short)f2bs((vals[16 + i] - mu) * rstd * n2g[c2] + n2b[c2]);
    }
}

// ---------------------------------------------------------------------------
// MLP: 32 tokens/wave (2 sets sharing weight loads), software-pipelined
// double-buffered slab (fc2 of step s overlaps fc1 of step s+1).
// 128 tokens / block, 256 thr, 3136 blocks. LDS 20.5 KB.
// ---------------------------------------------------------------------------
template <bool CLEAN>
__global__ __launch_bounds__(256) void mlp_kernel(
    const ushort* __restrict__ xsrc,
    const ushort* __restrict__ x1flat,
    const float* __restrict__ n2g, const float* __restrict__ n2b,
    const float* __restrict__ b1v, const float* __restrict__ b2v,
    const ushort* __restrict__ wf1, const ushort* __restrict__ wf2,
    float* __restrict__ out)
{
    __shared__ __align__(16) ushort hS[4][2][32][40];   // per-wave dbuf slab

    const int tid  = threadIdx.x;
    const int wave = tid >> 6, lane = tid & 63;
    const int cu   = lane & 15;
    const int g4   = lane >> 4;
    const int gk8  = g4 << 3;
    const int gr4  = g4 << 2;
    const int t0g  = blockIdx.x * 128;
    const int tokA = t0g + (wave << 5) + cu;   // set A token (rows 0..15)
    const int tokB = tokA + 16;                // set B token (rows 16..31)

    s16x8 aA0, aA1, aA2, aB0, aB1, aB2;
    ln_token<CLEAN>(xsrc, tokA, gk8, n2g, n2b, aA0, aA1, aA2);
    ln_token<CLEAN>(xsrc, tokB, gk8, n2g, n2b, aB0, aB1, aB2);

    // fc1 for h-cols [32s, 32s+32) of both sets -> slab[buf]
    auto fc1_step = [&](int s, int buf) {
        #pragma unroll
        for (int half = 0; half < 2; ++half) {
            int nc = ((2 * s + half) << 4) | cu;
            const ushort* bp = wf1 + nc * 96 + gk8;
            s16x8 b0 = *(const s16x8*)(bp);
            s16x8 b1 = *(const s16x8*)(bp + 32);
            s16x8 b2 = *(const s16x8*)(bp + 64);
            float bias = b1v[nc];
            f32x4 accA = {0.f, 0.f, 0.f, 0.f};
            accA = mfma16(aA0, b0, accA);
            accA = mfma16(aA1, b1, accA);
            accA = mfma16(aA2, b2, accA);
            f32x4 accB = {0.f, 0.f, 0.f, 0.f};
            accB = mfma16(aB0, b0, accB);
            accB = mfma16(aB1, b1, accB);
            accB = mfma16(aB2, b2, accB);
            #pragma unroll
            for (int r = 0; r < 4; ++r) {
                hS[wave][buf][gr4 + r][(half << 4) | cu]      = f2bs(gelu_f(accA[r] + bias));
                hS[wave][buf][16 + gr4 + r][(half << 4) | cu] = f2bs(gelu_f(accB[r] + bias));
            }
        }
    };

    f32x4 oaccA[6], oaccB[6];
    #pragma unroll
    for (int nt2 = 0; nt2 < 6; ++nt2) {
        oaccA[nt2] = (f32x4){0.f, 0.f, 0.f, 0.f};
        oaccB[nt2] = (f32x4){0.f, 0.f, 0.f, 0.f};
    }

    fc1_step(0, 0);                       // prologue
    for (int s = 0; s < 12; ++s) {
        int buf = s & 1;
        // read slab written one iteration ago (wave-private; lgkmcnt orders)
        s16x8 haA = *(const s16x8*)&hS[wave][buf][cu][gk8];
        s16x8 haB = *(const s16x8*)&hS[wave][buf][16 + cu][gk8];
        if (s < 11) fc1_step(s + 1, buf ^ 1);
        #pragma unroll
        for (int nt2 = 0; nt2 < 6; ++nt2) {
            int nc2 = (nt2 << 4) | cu;
            s16x8 bv = *(const s16x8*)&wf2[nc2 * 384 + s * 32 + gk8];
            oaccA[nt2] = mfma16(haA, bv, oaccA[nt2]);
            oaccB[nt2] = mfma16(haB, bv, oaccB[nt2]);
        }
    }

    // epilogue: bias + residual at un-permuted flat index
    const int trow = (wave << 5) + gr4;
    #pragma unroll
    for (int nt2 = 0; nt2 < 6; ++nt2) {
        int nc2 = (nt2 << 4) | cu;
        float bias = b2v[nc2];
        #pragma unroll
        for (int r = 0; r < 4; ++r) {
            int GA = (t0g + trow + r) * 96 + nc2;
            out[GA] = bias + oaccA[nt2][r] + bs2f(x1flat[GA]);
            int GB = GA + 16 * 96;
            out[GB] = bias + oaccB[nt2][r] + bs2f(x1flat[GB]);
        }
    }
}

// ---------------------------------------------------------------------------
extern "C" void kernel_launch(void* const* d_in, const int* in_sizes, int n_in,
                              void* d_out, int out_size, void* d_ws, size_t ws_size,
                              hipStream_t stream) {
    const float* x      = (const float*)d_in[0];
    const float* amask  = (const float*)d_in[1];
    const float* n1g    = (const float*)d_in[2];
    const float* n1b    = (const float*)d_in[3];
    const float* qkvw   = (const float*)d_in[4];
    const float* qkvb   = (const float*)d_in[5];
    const float* rpb    = (const float*)d_in[6];
    const float* projw  = (const float*)d_in[7];
    const float* projb  = (const float*)d_in[8];
    const float* n2g    = (const float*)d_in[9];
    const float* n2b    = (const float*)d_in[10];
    const float* w1     = (const float*)d_in[11];
    const float* b1     = (const float*)d_in[12];
    const float* w2     = (const float*)d_in[13];
    const float* b2     = (const float*)d_in[14];

    char* ws = (char*)d_ws;
    ushort* wq  = (ushort*)(ws);            // 27648 el
    ushort* wp  = (ushort*)(ws + 55296);    // 9216 el
    ushort* wf1 = (ushort*)(ws + 73728);    // 36864 el
    ushort* wf2 = (ushort*)(ws + 147456);   // 36864 el
    ushort* x1  = (ushort*)(ws + 262144);   // 38,535,168 el (77.07 MB)
    ushort* x1p = (ushort*)(ws + 77332480); // permuted copy (77.07 MB)
    float* out = (float*)d_out;

    const bool clean = (ws_size >= (size_t)154402816);

    prep_kernel<<<dim3(144), dim3(256), 0, stream>>>(qkvw, projw, w1, w2, wq, wp, wf1, wf2);

    attn_kernel<<<dim3(8192), dim3(256), 0, stream>>>(
        x, amask, n1g, n1b, qkvb, rpb, projb, wq, wp, x1);

    if (clean) {
        transpose_kernel<<<dim3(37632), dim3(256), 0, stream>>>(x1, x1p);
        mlp_kernel<true><<<dim3(3136), dim3(256), 0, stream>>>(
            x1p, x1, n2g, n2b, b1, b2, wf1, wf2, out);
    } else {
        mlp_kernel<false><<<dim3(3136), dim3(256), 0, stream>>>(
            x1, x1, n2g, n2b, b1, b2, wf1, wf2, out);
    }
}